// Round 5
// baseline (1252.838 us; speedup 1.0000x reference)
//
#include <hip/hip_runtime.h>
#include <hip/hip_bf16.h>
#include <math.h>

#define Nn  50000
#define NR  50048   // rows padded to 64
#define En  800000
#define DIN 500
#define Hd  128
#define Cc  40
#define Bb  10000
#define Ll  9
#define KT  5

typedef short bf16x8 __attribute__((ext_vector_type(8)));
typedef unsigned short u16x8 __attribute__((ext_vector_type(8)));
typedef float f32x4 __attribute__((ext_vector_type(4)));

__device__ inline float bf2f(unsigned short u) {
  union { unsigned int i; float f; } c; c.i = (unsigned int)u << 16; return c.f;
}
__device__ inline unsigned short f2bf(float f) {
  __hip_bfloat16 b = __float2bfloat16(f);
  return *(unsigned short*)&b;
}

// ---------------- weight packing into B-fragment layout ----------------
__global__ __launch_bounds__(256) void k_pack_w1(const float* __restrict__ W1,
                                                 unsigned short* __restrict__ W1p) {
  const int id = blockIdx.x * 256 + threadIdx.x;   // 16*4*128*8 = 65536
  if (id >= 65536) return;
  const int j = id & 7, col = (id >> 3) & 127, qk = id >> 10;  // qk = kk*4+quad
  const int k = (qk >> 2) * 32 + (qk & 3) * 8 + j;
  W1p[id] = f2bf((k < DIN) ? W1[(size_t)k * Hd + col] : 0.f);
}

// Wcat[l] = [W1l ; 0.5*W2l]  (K=256), same frag packing, 32768 elems/layer
__global__ __launch_bounds__(256) void k_pack_wc(const float* __restrict__ cw1,
    const float* __restrict__ cw2, unsigned short* __restrict__ Wcp) {
  const int id = blockIdx.x * 256 + threadIdx.x;   // 9*32768 = 294912
  if (id >= 294912) return;
  const int j = id & 7, col = (id >> 3) & 127, qk = (id >> 10) & 31, l = id >> 15;
  const int k = (qk >> 2) * 32 + (qk & 3) * 8 + j;  // 0..255
  float v;
  if (k < 128) v = cw1[((size_t)l * 128 + k) * 128 + col];
  else         v = 0.5f * cw2[((size_t)l * 128 + (k - 128)) * 128 + col];
  Wcp[id] = f2bf(v);
}

// ---------------- input GEMM (MFMA): hb = bf16(relu(x @ W1 + b1)) ----------------
__global__ __launch_bounds__(256) void k_in(const float* __restrict__ x,
    const unsigned short* __restrict__ W1p, const float* __restrict__ b1,
    unsigned short* __restrict__ hb, unsigned short* __restrict__ x0b) {
  const int tid = threadIdx.x;
  const int wv = tid >> 6, lane = tid & 63;
  const int lrow = lane & 15, quad = lane >> 4;
  const int row0 = blockIdx.x * 64;
  const int ar = row0 + wv * 16 + lrow;
  f32x4 acc[8];
#pragma unroll
  for (int t = 0; t < 8; ++t) acc[t] = (f32x4){0.f, 0.f, 0.f, 0.f};

  for (int kk = 0; kk < 16; ++kk) {
    const int kbase = kk * 32 + quad * 8;
    float av[8];
    if (ar < Nn) {
      if (kk < 15) {
        const float4 p0 = *(const float4*)(x + (size_t)ar * DIN + kbase);
        const float4 p1 = *(const float4*)(x + (size_t)ar * DIN + kbase + 4);
        av[0] = p0.x; av[1] = p0.y; av[2] = p0.z; av[3] = p0.w;
        av[4] = p1.x; av[5] = p1.y; av[6] = p1.z; av[7] = p1.w;
      } else {
#pragma unroll
        for (int j = 0; j < 8; ++j)
          av[j] = (kbase + j < DIN) ? x[(size_t)ar * DIN + kbase + j] : 0.f;
      }
    } else {
#pragma unroll
      for (int j = 0; j < 8; ++j) av[j] = 0.f;
    }
    bf16x8 af;
#pragma unroll
    for (int j = 0; j < 8; ++j) af[j] = (short)f2bf(av[j]);
#pragma unroll
    for (int nt = 0; nt < 8; ++nt) {
      const bf16x8 bf = *(const bf16x8*)(W1p + ((size_t)(kk * 4 + quad) * 128 + nt * 16 + lrow) * 8);
      acc[nt] = __builtin_amdgcn_mfma_f32_16x16x32_bf16(af, bf, acc[nt], 0, 0, 0);
    }
  }

  __shared__ float sacc[64 * 132];
#pragma unroll
  for (int nt = 0; nt < 8; ++nt)
#pragma unroll
    for (int i = 0; i < 4; ++i)
      sacc[(wv * 16 + quad * 4 + i) * 132 + nt * 16 + lrow] = acc[nt][i];
  __syncthreads();

  const int row = tid >> 2, cs = (tid & 3) * 32;
  const int gr = row0 + row;
  if (gr < Nn) {
#pragma unroll
    for (int g = 0; g < 4; ++g) {
      const int c0 = cs + g * 8;
      float v[8];
#pragma unroll
      for (int j = 0; j < 8; ++j)
        v[j] = fmaxf(sacc[row * 132 + c0 + j] + b1[c0 + j], 0.f);
      u16x8 ob;
#pragma unroll
      for (int j = 0; j < 8; ++j) ob[j] = f2bf(v[j]);
      *(u16x8*)(hb + (size_t)gr * Hd + c0) = ob;
      *(u16x8*)(x0b + (size_t)gr * Hd + c0) = ob;
    }
  }
}

// ---------------- CSR build ----------------
__global__ void k_hist(const int* __restrict__ rows, int* __restrict__ counts) {
  int e = blockIdx.x * 256 + threadIdx.x;
  if (e < En) atomicAdd(&counts[rows[e]], 1);
}

// Parallel scan: each block redundantly sums its prefix (L2-resident, fully
// parallel) then scans its own 256-element segment.
__global__ __launch_bounds__(256) void k_scan2(const int* __restrict__ counts,
                                               int* __restrict__ rptr) {
  __shared__ int sdata[256];
  const int b = blockIdx.x, tid = threadIdx.x;
  const int npre = b << 8;
  int s0 = 0, s1 = 0, s2 = 0, s3 = 0;
  int i = tid;
  for (; i + 768 < npre; i += 1024) {
    s0 += counts[i]; s1 += counts[i + 256]; s2 += counts[i + 512]; s3 += counts[i + 768];
  }
  for (; i < npre; i += 256) s0 += counts[i];
  sdata[tid] = s0 + s1 + s2 + s3;
  __syncthreads();
  for (int off = 128; off > 0; off >>= 1) {
    if (tid < off) sdata[tid] += sdata[tid + off];
    __syncthreads();
  }
  const int base = sdata[0];
  __syncthreads();
  const int gi = npre + tid;
  int v = (gi < Nn) ? counts[gi] : 0;
  sdata[tid] = v;
  __syncthreads();
  for (int off = 1; off < 256; off <<= 1) {
    int t = (tid >= off) ? sdata[tid - off] : 0;
    __syncthreads();
    sdata[tid] += t;
    __syncthreads();
  }
  if (gi < Nn) rptr[gi + 1] = base + sdata[tid];
  if (b == 0 && tid == 0) rptr[0] = 0;
}

// scatter (col,w) as a single int2 pair: one 8B index load per edge
__global__ void k_scatter(const int* __restrict__ rows, const int* __restrict__ cols,
                          const float* __restrict__ w, const int* __restrict__ ptr,
                          int* __restrict__ fill, int2* __restrict__ cpair) {
  int e = blockIdx.x * 256 + threadIdx.x;
  if (e >= En) return;
  int r = rows[e];
  int pos = atomicAdd(&fill[r], 1);
  int d = ptr[r] + pos;
  int2 pr; pr.x = cols[e]; pr.y = __float_as_int(w[e]);
  cpair[d] = pr;
}

// ---------------- FUSED spmm + layer ----------------
// Phase A: per-block spmm for its own 64 rows -> bf16 tile in LDS (identical
// rounding to the old global pb). Phase B: the layer GEMM consumes the tile
// from LDS (A-frags kk<4 and epilogue pj). Removes the pb global round-trip
// and halves launch count. hb is double-buffered (hbr read / hbw write) since
// blocks gather neighbors' hbr while producing hbw.
#define PB_LD 136
__global__ __launch_bounds__(256) void k_fused(const int* __restrict__ ptr,
    const int2* __restrict__ cpair, const unsigned short* __restrict__ hbr,
    const unsigned short* __restrict__ x0b, const unsigned short* __restrict__ Wcp,
    unsigned short* __restrict__ hbw, float beta) {
  __shared__ __align__(16) unsigned short pb_s[64 * PB_LD];
  __shared__ float sacc[64 * 132];
  const int tid = threadIdx.x;
  const int wv = tid >> 6, lane = tid & 63;
  const int g = lane >> 4;        // edge group 0..3
  const int fl = lane & 15;       // feature lane
  const int row0 = blockIdx.x * 64;

  // ---- phase A: spmm for rows row0 + wv*16 + r, r = 0..15
  for (int r = 0; r < 16; ++r) {
    const int row = row0 + wv * 16 + r;
    float acc[8];
#pragma unroll
    for (int j = 0; j < 8; ++j) acc[j] = 0.f;

    auto acc8 = [&](uint4 v, float w) {
      union { unsigned int i; float f; } t;
      t.i = v.x << 16;         acc[0] += w * t.f;
      t.i = v.x & 0xFFFF0000u; acc[1] += w * t.f;
      t.i = v.y << 16;         acc[2] += w * t.f;
      t.i = v.y & 0xFFFF0000u; acc[3] += w * t.f;
      t.i = v.z << 16;         acc[4] += w * t.f;
      t.i = v.z & 0xFFFF0000u; acc[5] += w * t.f;
      t.i = v.w << 16;         acc[6] += w * t.f;
      t.i = v.w & 0xFFFF0000u; acc[7] += w * t.f;
    };

    if (row < Nn) {
      const int s = ptr[row], e_end = ptr[row + 1];
      int e = s + g;
      for (; e + 12 < e_end; e += 16) {
        const int2 p0 = cpair[e];
        const int2 p1 = cpair[e + 4];
        const int2 p2 = cpair[e + 8];
        const int2 p3 = cpair[e + 12];
        const uint4 v0 = *(const uint4*)(hbr + (size_t)p0.x * Hd + fl * 8);
        const uint4 v1 = *(const uint4*)(hbr + (size_t)p1.x * Hd + fl * 8);
        const uint4 v2 = *(const uint4*)(hbr + (size_t)p2.x * Hd + fl * 8);
        const uint4 v3 = *(const uint4*)(hbr + (size_t)p3.x * Hd + fl * 8);
        acc8(v0, __int_as_float(p0.y)); acc8(v1, __int_as_float(p1.y));
        acc8(v2, __int_as_float(p2.y)); acc8(v3, __int_as_float(p3.y));
      }
      for (; e + 4 < e_end; e += 8) {
        const int2 p0 = cpair[e];
        const int2 p1 = cpair[e + 4];
        const uint4 v0 = *(const uint4*)(hbr + (size_t)p0.x * Hd + fl * 8);
        const uint4 v1 = *(const uint4*)(hbr + (size_t)p1.x * Hd + fl * 8);
        acc8(v0, __int_as_float(p0.y)); acc8(v1, __int_as_float(p1.y));
      }
      if (e < e_end) {
        const int2 p0 = cpair[e];
        const uint4 v = *(const uint4*)(hbr + (size_t)p0.x * Hd + fl * 8);
        acc8(v, __int_as_float(p0.y));
      }
    }
#pragma unroll
    for (int j = 0; j < 8; ++j) acc[j] += __shfl_xor(acc[j], 16);
#pragma unroll
    for (int j = 0; j < 8; ++j) acc[j] += __shfl_xor(acc[j], 32);
    if (g == 0) {
      uint4 o;
      o.x = (unsigned int)f2bf(0.5f * acc[0]) | ((unsigned int)f2bf(0.5f * acc[1]) << 16);
      o.y = (unsigned int)f2bf(0.5f * acc[2]) | ((unsigned int)f2bf(0.5f * acc[3]) << 16);
      o.z = (unsigned int)f2bf(0.5f * acc[4]) | ((unsigned int)f2bf(0.5f * acc[5]) << 16);
      o.w = (unsigned int)f2bf(0.5f * acc[6]) | ((unsigned int)f2bf(0.5f * acc[7]) << 16);
      *(uint4*)&pb_s[(wv * 16 + r) * PB_LD + fl * 8] = o;
    }
  }
  __syncthreads();

  // ---- phase B: layer GEMM (A = [pb_s ; x0b], B = Wcp layer slice)
  const int lrow = lane & 15, quad = lane >> 4;
  const int ar = row0 + wv * 16 + lrow;
  const int arl = wv * 16 + lrow;
  f32x4 gacc[8];
#pragma unroll
  for (int t = 0; t < 8; ++t) gacc[t] = (f32x4){0.f, 0.f, 0.f, 0.f};

#pragma unroll
  for (int kk = 0; kk < 8; ++kk) {
    const int ko = (kk & 3) * 32 + quad * 8;
    bf16x8 af;
    if (kk < 4) af = *(const bf16x8*)&pb_s[arl * PB_LD + ko];
    else        af = *(const bf16x8*)(x0b + (size_t)ar * Hd + ko);
#pragma unroll
    for (int nt = 0; nt < 8; ++nt) {
      const bf16x8 bf = *(const bf16x8*)(Wcp + ((size_t)(kk * 4 + quad) * 128 + nt * 16 + lrow) * 8);
      gacc[nt] = __builtin_amdgcn_mfma_f32_16x16x32_bf16(af, bf, gacc[nt], 0, 0, 0);
    }
  }

#pragma unroll
  for (int nt = 0; nt < 8; ++nt)
#pragma unroll
    for (int i = 0; i < 4; ++i)
      sacc[(wv * 16 + quad * 4 + i) * 132 + nt * 16 + lrow] = gacc[nt][i];
  __syncthreads();

  const int row = tid >> 2, cs = (tid & 3) * 32;
  const int gr = row0 + row;
  if (gr < Nn) {
    const float om = 1.f - beta;
#pragma unroll
    for (int gg = 0; gg < 4; ++gg) {
      const int c0 = cs + gg * 8;
      const u16x8 pv = *(const u16x8*)&pb_s[row * PB_LD + c0];
      const u16x8 xv = *(const u16x8*)(x0b + (size_t)gr * Hd + c0);
      const u16x8 hv = *(const u16x8*)(hbr + (size_t)gr * Hd + c0);
      float nv[8];
#pragma unroll
      for (int j = 0; j < 8; ++j) {
        const float gemm = sacc[row * 132 + c0 + j];
        const float pj = bf2f(pv[j]);
        const float xj = bf2f(xv[j]);
        const float outv = om * (pj + 0.5f * xj) + beta * gemm;
        nv[j] = fmaxf(bf2f(hv[j]) + outv, 0.f);
      }
      u16x8 ob;
#pragma unroll
      for (int j = 0; j < 8; ++j) ob[j] = f2bf(nv[j]);
      *(u16x8*)(hbw + (size_t)gr * Hd + c0) = ob;
    }
  }
}

// ---------------- head (reads bf16 hb) ----------------
__global__ __launch_bounds__(256) void k_head(const unsigned short* __restrict__ hb,
    const float* __restrict__ W2, const float* __restrict__ b2,
    unsigned short* __restrict__ anb, float* __restrict__ p_lc,
    float* __restrict__ out_emb) {
  const int wid = (blockIdx.x * 256 + threadIdx.x) >> 6;
  const int lane = threadIdx.x & 63;
  if (wid >= Bb) return;
  const unsigned short* hr = hb + (size_t)wid * Hd;
  const float v0 = bf2f(hr[lane]), v1 = bf2f(hr[lane + 64]);
  out_emb[wid * Hd + lane] = v0;
  out_emb[wid * Hd + lane + 64] = v1;
  float ss = v0 * v0 + v1 * v1;
#pragma unroll
  for (int off = 32; off > 0; off >>= 1) ss += __shfl_xor(ss, off);
  const float inv = 1.f / fmaxf(sqrtf(ss), 1e-8f);
  anb[wid * Hd + lane] = f2bf(v0 * inv);
  anb[wid * Hd + lane + 64] = f2bf(v1 * inv);
  float l = 0.f;
  if (lane < Cc) {
    for (int k = 0; k < Hd; ++k) l += bf2f(hr[k]) * W2[k * Cc + lane];
    l += b2[lane];
  }
  float lm = (lane < Cc) ? l : -3.0e38f;
#pragma unroll
  for (int off = 32; off > 0; off >>= 1) lm = fmaxf(lm, __shfl_xor(lm, off));
  float ex = (lane < Cc) ? expf(l - lm) : 0.f;
#pragma unroll
  for (int off = 32; off > 0; off >>= 1) ex += __shfl_xor(ex, off);
  const float lse = logf(ex);
  if (lane < Cc) p_lc[wid * Cc + lane] = l - lm - lse;
}

// ---------------- fused sim = an@an^T (bf16 MFMA) with running top-5 ----------
// r4 analysis: bookkeeping (~576 cyc/tile) is the VALU cost; near structural
// floor for this decomposition. Left unchanged this round.
// (Guard-free full tiles NaN'd in r5/r6 — do not retry.)
#define CH_N  8
#define CH_SZ 1250
#define SB_LD 136
__global__ __launch_bounds__(256, 2) void k_simtopk(const unsigned short* __restrict__ anb,
    float* __restrict__ cval, int* __restrict__ cidx) {
  __shared__ __align__(16) unsigned short sb[64 * SB_LD];
  const int rt = blockIdx.x / CH_N;
  const int chunk = blockIdx.x % CH_N;
  const int row0 = rt * 64;
  const int cbeg = chunk * CH_SZ;
  const int cend = cbeg + CH_SZ;
  const int tid = threadIdx.x;
  const int wv = tid >> 6;
  const int lane = tid & 63;
  const int lrow = lane & 15;
  const int quad = lane >> 4;

  union Frag { uint4 u4; bf16x8 v; };
  bf16x8 afr[4];
  const int ar = row0 + wv * 16 + lrow;
#pragma unroll
  for (int kq = 0; kq < 4; ++kq) {
    Frag f;
    f.u4 = make_uint4(0u, 0u, 0u, 0u);
    if (ar < Bb) f.u4 = *(const uint4*)(anb + (size_t)ar * Hd + kq * 32 + quad * 8);
    afr[kq] = f.v;
  }

  float bv[4][KT];
  int bi[4][KT];
#pragma unroll
  for (int r = 0; r < 4; ++r)
#pragma unroll
    for (int t = 0; t < KT; ++t) { bv[r][t] = -3.0e38f; bi[r][t] = 0x7fffffff; }
  float minthr = -3.0e38f;   // min over the 4 rows' current 5th-best

  const int ntile = (CH_SZ + 63) / 64;
  for (int t = 0; t < ntile; ++t) {
    const int c0 = cbeg + t * 64;
    __syncthreads();
    for (int i = tid; i < 1024; i += 256) {
      const int r = i >> 4, ch = i & 15;
      const int gc = c0 + r;
      uint4 v = make_uint4(0u, 0u, 0u, 0u);
      if (gc < cend) v = *(const uint4*)(anb + (size_t)gc * Hd + ch * 8);
      *(uint4*)&sb[r * SB_LD + ch * 8] = v;
    }
    __syncthreads();
#pragma unroll
    for (int sub = 0; sub < 4; ++sub) {
      f32x4 acc = {0.f, 0.f, 0.f, 0.f};
      const int scol = sub * 16 + lrow;
#pragma unroll
      for (int kq = 0; kq < 4; ++kq) {
        bf16x8 bfr = *(const bf16x8*)&sb[scol * SB_LD + kq * 32 + quad * 8];
        acc = __builtin_amdgcn_mfma_f32_16x16x32_bf16(afr[kq], bfr, acc, 0, 0, 0);
      }
      const int gc = c0 + scol;
      const bool ok = gc < cend;
      float vv[4];
#pragma unroll
      for (int i = 0; i < 4; ++i) vv[i] = ok ? acc[i] : -3.0e38f;
      const float mx = fmaxf(fmaxf(vv[0], vv[1]), fmaxf(vv[2], vv[3]));
      if (mx > minthr) {
#pragma unroll
        for (int i = 0; i < 4; ++i) {
          const float v = vv[i];
          if (v > bv[i][KT - 1]) {
            float tv = v; int ti = gc;
#pragma unroll
            for (int s = 0; s < KT; ++s) {
              if (tv > bv[i][s]) {
                float ov = bv[i][s]; int oi = bi[i][s];
                bv[i][s] = tv; bi[i][s] = ti; tv = ov; ti = oi;
              }
            }
          }
        }
        minthr = fminf(fminf(bv[0][KT - 1], bv[1][KT - 1]),
                       fminf(bv[2][KT - 1], bv[3][KT - 1]));
      }
    }
  }

  // In-register butterfly merge across the 16 lanes (lrow) that share each
  // output row.
#pragma unroll
  for (int off = 1; off < 16; off <<= 1) {
#pragma unroll
    for (int i = 0; i < 4; ++i) {
      float ov[KT]; int oi[KT];
#pragma unroll
      for (int t = 0; t < KT; ++t) {
        ov[t] = __shfl_xor(bv[i][t], off);
        oi[t] = __shfl_xor(bi[i][t], off);
      }
#pragma unroll
      for (int t = 0; t < KT; ++t) {
        float v = ov[t]; int id = oi[t];
        if (v > bv[i][KT - 1] || (v == bv[i][KT - 1] && id < bi[i][KT - 1])) {
#pragma unroll
          for (int s = 0; s < KT; ++s) {
            const bool take = (v > bv[i][s]) || (v == bv[i][s] && id < bi[i][s]);
            if (take) {
              float tv = bv[i][s]; int ti = bi[i][s];
              bv[i][s] = v; bi[i][s] = id; v = tv; id = ti;
            }
          }
        }
      }
    }
  }

  if (lrow == 0) {
#pragma unroll
    for (int i = 0; i < 4; ++i) {
      const int gr = row0 + wv * 16 + quad * 4 + i;
      if (gr < Bb) {
#pragma unroll
        for (int t = 0; t < KT; ++t) {
          cval[(size_t)gr * (CH_N * KT) + chunk * KT + t] = bv[i][t];
          cidx[(size_t)gr * (CH_N * KT) + chunk * KT + t] = bi[i][t];
        }
      }
    }
  }
}

// ---------------- final ----------------
__global__ __launch_bounds__(256) void k_final(const float* __restrict__ cval,
    const int* __restrict__ cidx, const int* __restrict__ y,
    const float* __restrict__ p_lc, float* __restrict__ out_final) {
  const int b = blockIdx.x * 256 + threadIdx.x;
  if (b >= Bb) return;
  float tv5[KT]; int ti5[KT];
#pragma unroll
  for (int t = 0; t < KT; ++t) { tv5[t] = -3.0e38f; ti5[t] = 0x7fffffff; }
  for (int m = 0; m < CH_N * KT; ++m) {
    float v = cval[(size_t)b * (CH_N * KT) + m]; int id = cidx[(size_t)b * (CH_N * KT) + m];
    if (v > tv5[KT - 1] || (v == tv5[KT - 1] && id < ti5[KT - 1])) {
#pragma unroll
      for (int t = 0; t < KT; ++t) {
        if (v > tv5[t] || (v == tv5[t] && id < ti5[t])) {
          float ov = tv5[t]; int oi = ti5[t];
          tv5[t] = v; ti5[t] = id; v = ov; id = oi;
        }
      }
    }
  }
  float w[KT]; int cls[KT];
#pragma unroll
  for (int t = 0; t < KT; ++t) { w[t] = expf(tv5[t]); cls[t] = y[ti5[t]]; }
  float m = -3.0e38f;
  for (int c = 0; c < Cc; ++c) {
    float f = 0.f;
#pragma unroll
    for (int t = 0; t < KT; ++t) f += (cls[t] == c) ? w[t] : 0.f;
    m = fmaxf(m, f);
  }
  float s = 0.f;
  for (int c = 0; c < Cc; ++c) {
    float f = 0.f;
#pragma unroll
    for (int t = 0; t < KT; ++t) f += (cls[t] == c) ? w[t] : 0.f;
    s += expf(f - m);
  }
  const float lse = logf(s);
  for (int c = 0; c < Cc; ++c) {
    float f = 0.f;
#pragma unroll
    for (int t = 0; t < KT; ++t) f += (cls[t] == c) ? w[t] : 0.f;
    out_final[b * Cc + c] = 0.5f * p_lc[b * Cc + c] + 0.5f * (f - m - lse);
  }
}

extern "C" void kernel_launch(void* const* d_in, const int* in_sizes, int n_in,
                              void* d_out, int out_size, void* d_ws, size_t ws_size,
                              hipStream_t stream) {
  const float* x  = (const float*)d_in[0];
  const int* erow = (const int*)d_in[1];
  const int* ecol = erow + En;
  const float* ew = (const float*)d_in[2];
  const int* y    = (const int*)d_in[3];
  const float* W1 = (const float*)d_in[5];
  const float* b1 = (const float*)d_in[6];
  const float* cw1 = (const float*)d_in[7];
  const float* cw2 = (const float*)d_in[8];
  const float* W2 = (const float*)d_in[9];
  const float* b2 = (const float*)d_in[10];
  float* out = (float*)d_out;

  float* ws = (float*)d_ws;
  size_t off = 0;
  float* plc = ws + off; off += (size_t)Bb * Cc;
  float* cval = ws + off; off += (size_t)Bb * (CH_N * KT);
  int* cidx  = (int*)(ws + off); off += (size_t)Bb * (CH_N * KT);
  int* counts = (int*)(ws + off); off += Nn;
  int* fill   = (int*)(ws + off); off += Nn;
  int* rptr   = (int*)(ws + off); off += Nn + 4;
  int2* cpair = (int2*)(ws + off); off += (size_t)2 * En;   // even offset -> 8B aligned
  unsigned short* anb = (unsigned short*)(ws + off); off += (size_t)Bb * Hd / 2;
  unsigned short* hba = (unsigned short*)(ws + off); off += (size_t)NR * Hd / 2;
  unsigned short* hbb = (unsigned short*)(ws + off); off += (size_t)NR * Hd / 2;
  unsigned short* x0b = (unsigned short*)(ws + off); off += (size_t)NR * Hd / 2;
  unsigned short* W1p = (unsigned short*)(ws + off); off += 65536 / 2;
  unsigned short* Wcp = (unsigned short*)(ws + off); off += 294912 / 2;

  k_pack_w1<<<256, 256, 0, stream>>>(W1, W1p);
  k_pack_wc<<<1152, 256, 0, stream>>>(cw1, cw2, Wcp);
  k_in<<<NR / 64, 256, 0, stream>>>(x, W1p, b1, hba, x0b);
  hipMemsetAsync(counts, 0, (size_t)2 * Nn * sizeof(int), stream);
  k_hist<<<(En + 255) / 256, 256, 0, stream>>>(erow, counts);
  k_scan2<<<(Nn + 255) / 256, 256, 0, stream>>>(counts, rptr);
  k_scatter<<<(En + 255) / 256, 256, 0, stream>>>(erow, ecol, ew, rptr, fill, cpair);
  unsigned short* hcur = hba;
  unsigned short* hnxt = hbb;
  for (int l = 0; l < Ll; ++l) {
    const float beta = logf(1.0f / (float)(l + 1) + 1.0f);
    k_fused<<<NR / 64, 256, 0, stream>>>(rptr, cpair, hcur, x0b,
                                         Wcp + (size_t)l * 32768, hnxt, beta);
    unsigned short* t = hcur; hcur = hnxt; hnxt = t;
  }
  k_head<<<(Bb * 64) / 256, 256, 0, stream>>>(hcur, W2, b2, anb, plc, out + (size_t)Bb * Cc);
  k_simtopk<<<((Bb + 63) / 64) * CH_N, 256, 0, stream>>>(anb, cval, cidx);
  k_final<<<(Bb + 255) / 256, 256, 0, stream>>>(cval, cidx, y, plc, out);
}

// Round 7
// 1012.882 us; speedup vs baseline: 1.2369x; 1.2369x over previous
//
#include <hip/hip_runtime.h>
#include <hip/hip_bf16.h>
#include <math.h>

#define Nn  50000
#define NR  50048   // rows padded to 64
#define En  800000
#define DIN 500
#define Hd  128
#define Cc  40
#define Bb  10000
#define Ll  9
#define KT  5

typedef short bf16x8 __attribute__((ext_vector_type(8)));
typedef unsigned short u16x8 __attribute__((ext_vector_type(8)));
typedef float f32x4 __attribute__((ext_vector_type(4)));
typedef unsigned long long u64;

__device__ inline float bf2f(unsigned short u) {
  union { unsigned int i; float f; } c; c.i = (unsigned int)u << 16; return c.f;
}
__device__ inline unsigned short f2bf(float f) {
  __hip_bfloat16 b = __float2bfloat16(f);
  return *(unsigned short*)&b;
}
// monotone float<->uint key: k ascending <=> float ascending
__device__ inline unsigned int mkkey(float v) {
  unsigned int u = __float_as_uint(v);
  unsigned int s = (unsigned int)((int)u >> 31);
  return u ^ (0x80000000u | s);
}
__device__ inline float unkey(unsigned int k) {
  unsigned int s = (unsigned int)((int)k >> 31);
  unsigned int mask = 0x80000000u | ~s;
  return __uint_as_float(k ^ mask);
}

// ---------------- weight packing into B-fragment layout ----------------
__global__ __launch_bounds__(256) void k_pack_w1(const float* __restrict__ W1,
                                                 unsigned short* __restrict__ W1p) {
  const int id = blockIdx.x * 256 + threadIdx.x;   // 16*4*128*8 = 65536
  if (id >= 65536) return;
  const int j = id & 7, col = (id >> 3) & 127, qk = id >> 10;  // qk = kk*4+quad
  const int k = (qk >> 2) * 32 + (qk & 3) * 8 + j;
  W1p[id] = f2bf((k < DIN) ? W1[(size_t)k * Hd + col] : 0.f);
}

// Wcat[l] = [W1l ; 0.5*W2l]  (K=256), same frag packing, 32768 elems/layer
__global__ __launch_bounds__(256) void k_pack_wc(const float* __restrict__ cw1,
    const float* __restrict__ cw2, unsigned short* __restrict__ Wcp) {
  const int id = blockIdx.x * 256 + threadIdx.x;   // 9*32768 = 294912
  if (id >= 294912) return;
  const int j = id & 7, col = (id >> 3) & 127, qk = (id >> 10) & 31, l = id >> 15;
  const int k = (qk >> 2) * 32 + (qk & 3) * 8 + j;  // 0..255
  float v;
  if (k < 128) v = cw1[((size_t)l * 128 + k) * 128 + col];
  else         v = 0.5f * cw2[((size_t)l * 128 + (k - 128)) * 128 + col];
  Wcp[id] = f2bf(v);
}

// ---------------- input GEMM (MFMA): hb = bf16(relu(x @ W1 + b1)) ----------------
__global__ __launch_bounds__(256) void k_in(const float* __restrict__ x,
    const unsigned short* __restrict__ W1p, const float* __restrict__ b1,
    unsigned short* __restrict__ hb, unsigned short* __restrict__ x0b) {
  const int tid = threadIdx.x;
  const int wv = tid >> 6, lane = tid & 63;
  const int lrow = lane & 15, quad = lane >> 4;
  const int row0 = blockIdx.x * 64;
  const int ar = row0 + wv * 16 + lrow;
  f32x4 acc[8];
#pragma unroll
  for (int t = 0; t < 8; ++t) acc[t] = (f32x4){0.f, 0.f, 0.f, 0.f};

  for (int kk = 0; kk < 16; ++kk) {
    const int kbase = kk * 32 + quad * 8;
    float av[8];
    if (ar < Nn) {
      if (kk < 15) {
        const float4 p0 = *(const float4*)(x + (size_t)ar * DIN + kbase);
        const float4 p1 = *(const float4*)(x + (size_t)ar * DIN + kbase + 4);
        av[0] = p0.x; av[1] = p0.y; av[2] = p0.z; av[3] = p0.w;
        av[4] = p1.x; av[5] = p1.y; av[6] = p1.z; av[7] = p1.w;
      } else {
#pragma unroll
        for (int j = 0; j < 8; ++j)
          av[j] = (kbase + j < DIN) ? x[(size_t)ar * DIN + kbase + j] : 0.f;
      }
    } else {
#pragma unroll
      for (int j = 0; j < 8; ++j) av[j] = 0.f;
    }
    bf16x8 af;
#pragma unroll
    for (int j = 0; j < 8; ++j) af[j] = (short)f2bf(av[j]);
#pragma unroll
    for (int nt = 0; nt < 8; ++nt) {
      const bf16x8 bf = *(const bf16x8*)(W1p + ((size_t)(kk * 4 + quad) * 128 + nt * 16 + lrow) * 8);
      acc[nt] = __builtin_amdgcn_mfma_f32_16x16x32_bf16(af, bf, acc[nt], 0, 0, 0);
    }
  }

  __shared__ float sacc[64 * 132];
#pragma unroll
  for (int nt = 0; nt < 8; ++nt)
#pragma unroll
    for (int i = 0; i < 4; ++i)
      sacc[(wv * 16 + quad * 4 + i) * 132 + nt * 16 + lrow] = acc[nt][i];
  __syncthreads();

  const int row = tid >> 2, cs = (tid & 3) * 32;
  const int gr = row0 + row;
  if (gr < Nn) {
#pragma unroll
    for (int g = 0; g < 4; ++g) {
      const int c0 = cs + g * 8;
      float v[8];
#pragma unroll
      for (int j = 0; j < 8; ++j)
        v[j] = fmaxf(sacc[row * 132 + c0 + j] + b1[c0 + j], 0.f);
      u16x8 ob;
#pragma unroll
      for (int j = 0; j < 8; ++j) ob[j] = f2bf(v[j]);
      *(u16x8*)(hb + (size_t)gr * Hd + c0) = ob;
      *(u16x8*)(x0b + (size_t)gr * Hd + c0) = ob;
    }
  }
}

// ---------------- CSR build ----------------
__global__ void k_hist(const int* __restrict__ rows, int* __restrict__ counts) {
  int e = blockIdx.x * 256 + threadIdx.x;
  if (e < En) atomicAdd(&counts[rows[e]], 1);
}

// Parallel scan: each block redundantly sums its prefix (L2-resident, fully
// parallel) then scans its own 256-element segment.
__global__ __launch_bounds__(256) void k_scan2(const int* __restrict__ counts,
                                               int* __restrict__ rptr) {
  __shared__ int sdata[256];
  const int b = blockIdx.x, tid = threadIdx.x;
  const int npre = b << 8;
  int s0 = 0, s1 = 0, s2 = 0, s3 = 0;
  int i = tid;
  for (; i + 768 < npre; i += 1024) {
    s0 += counts[i]; s1 += counts[i + 256]; s2 += counts[i + 512]; s3 += counts[i + 768];
  }
  for (; i < npre; i += 256) s0 += counts[i];
  sdata[tid] = s0 + s1 + s2 + s3;
  __syncthreads();
  for (int off = 128; off > 0; off >>= 1) {
    if (tid < off) sdata[tid] += sdata[tid + off];
    __syncthreads();
  }
  const int base = sdata[0];
  __syncthreads();
  const int gi = npre + tid;
  int v = (gi < Nn) ? counts[gi] : 0;
  sdata[tid] = v;
  __syncthreads();
  for (int off = 1; off < 256; off <<= 1) {
    int t = (tid >= off) ? sdata[tid - off] : 0;
    __syncthreads();
    sdata[tid] += t;
    __syncthreads();
  }
  if (gi < Nn) rptr[gi + 1] = base + sdata[tid];
  if (b == 0 && tid == 0) rptr[0] = 0;
}

// scatter (col,w) as a single int2 pair: one 8B index load per edge in spmm
__global__ void k_scatter(const int* __restrict__ rows, const int* __restrict__ cols,
                          const float* __restrict__ w, const int* __restrict__ ptr,
                          int* __restrict__ fill, int2* __restrict__ cpair) {
  int e = blockIdx.x * 256 + threadIdx.x;
  if (e >= En) return;
  int r = rows[e];
  int pos = atomicAdd(&fill[r], 1);
  int d = ptr[r] + pos;
  int2 pr; pr.x = cols[e]; pr.y = __float_as_int(w[e]);
  cpair[d] = pr;
}

// ---------------- SpMM: pb = bf16(0.5 * segment_sum(w * hb[col])) --------------
// r4 known-good: one row per wave (50000 independent waves = the TLP that the
// r5 fusion destroyed); edges strided over 4 lane-groups of 16; uint4 loads.
__global__ __launch_bounds__(256) void k_spmm(const int* __restrict__ ptr,
    const int2* __restrict__ cpair,
    const unsigned short* __restrict__ hb, unsigned short* __restrict__ pb) {
  const int wave = (blockIdx.x * 256 + threadIdx.x) >> 6;
  const int lane = threadIdx.x & 63;
  const int g = lane >> 4;        // edge group 0..3
  const int fl = lane & 15;       // feature lane: feats fl*8 .. fl*8+7
  if (wave >= Nn) return;
  const int s = ptr[wave], e_end = ptr[wave + 1];
  float acc[8];
#pragma unroll
  for (int j = 0; j < 8; ++j) acc[j] = 0.f;

  auto acc8 = [&](uint4 v, float w) {
    union { unsigned int i; float f; } t;
    t.i = v.x << 16;         acc[0] += w * t.f;
    t.i = v.x & 0xFFFF0000u; acc[1] += w * t.f;
    t.i = v.y << 16;         acc[2] += w * t.f;
    t.i = v.y & 0xFFFF0000u; acc[3] += w * t.f;
    t.i = v.z << 16;         acc[4] += w * t.f;
    t.i = v.z & 0xFFFF0000u; acc[5] += w * t.f;
    t.i = v.w << 16;         acc[6] += w * t.f;
    t.i = v.w & 0xFFFF0000u; acc[7] += w * t.f;
  };

  int e = s + g;
  for (; e + 12 < e_end; e += 16) {
    const int2 p0 = cpair[e];
    const int2 p1 = cpair[e + 4];
    const int2 p2 = cpair[e + 8];
    const int2 p3 = cpair[e + 12];
    const uint4 v0 = *(const uint4*)(hb + (size_t)p0.x * Hd + fl * 8);
    const uint4 v1 = *(const uint4*)(hb + (size_t)p1.x * Hd + fl * 8);
    const uint4 v2 = *(const uint4*)(hb + (size_t)p2.x * Hd + fl * 8);
    const uint4 v3 = *(const uint4*)(hb + (size_t)p3.x * Hd + fl * 8);
    acc8(v0, __int_as_float(p0.y)); acc8(v1, __int_as_float(p1.y));
    acc8(v2, __int_as_float(p2.y)); acc8(v3, __int_as_float(p3.y));
  }
  for (; e + 4 < e_end; e += 8) {
    const int2 p0 = cpair[e];
    const int2 p1 = cpair[e + 4];
    const uint4 v0 = *(const uint4*)(hb + (size_t)p0.x * Hd + fl * 8);
    const uint4 v1 = *(const uint4*)(hb + (size_t)p1.x * Hd + fl * 8);
    acc8(v0, __int_as_float(p0.y)); acc8(v1, __int_as_float(p1.y));
  }
  if (e < e_end) {
    const int2 p0 = cpair[e];
    const uint4 v = *(const uint4*)(hb + (size_t)p0.x * Hd + fl * 8);
    acc8(v, __int_as_float(p0.y));
  }
#pragma unroll
  for (int j = 0; j < 8; ++j) acc[j] += __shfl_xor(acc[j], 16);
#pragma unroll
  for (int j = 0; j < 8; ++j) acc[j] += __shfl_xor(acc[j], 32);
  if (g == 0) {
    uint4 o;
    o.x = (unsigned int)f2bf(0.5f * acc[0]) | ((unsigned int)f2bf(0.5f * acc[1]) << 16);
    o.y = (unsigned int)f2bf(0.5f * acc[2]) | ((unsigned int)f2bf(0.5f * acc[3]) << 16);
    o.z = (unsigned int)f2bf(0.5f * acc[4]) | ((unsigned int)f2bf(0.5f * acc[5]) << 16);
    o.w = (unsigned int)f2bf(0.5f * acc[6]) | ((unsigned int)f2bf(0.5f * acc[7]) << 16);
    *(uint4*)(pb + (size_t)wave * Hd + fl * 8) = o;
  }
}

// ---------------- layer (MFMA), residual in bf16 hb (in-place) ----------------
__global__ __launch_bounds__(256) void k_layer(const unsigned short* __restrict__ pb,
    const unsigned short* __restrict__ x0b, const unsigned short* __restrict__ Wcp,
    unsigned short* __restrict__ hb, float beta) {
  const int tid = threadIdx.x;
  const int wv = tid >> 6, lane = tid & 63;
  const int lrow = lane & 15, quad = lane >> 4;
  const int row0 = blockIdx.x * 64;
  const int ar = row0 + wv * 16 + lrow;
  f32x4 acc[8];
#pragma unroll
  for (int t = 0; t < 8; ++t) acc[t] = (f32x4){0.f, 0.f, 0.f, 0.f};

#pragma unroll
  for (int kk = 0; kk < 8; ++kk) {
    const unsigned short* src = (kk < 4) ? pb : x0b;
    const int ko = (kk & 3) * 32 + quad * 8;
    const bf16x8 af = *(const bf16x8*)(src + (size_t)ar * Hd + ko);
#pragma unroll
    for (int nt = 0; nt < 8; ++nt) {
      const bf16x8 bf = *(const bf16x8*)(Wcp + ((size_t)(kk * 4 + quad) * 128 + nt * 16 + lrow) * 8);
      acc[nt] = __builtin_amdgcn_mfma_f32_16x16x32_bf16(af, bf, acc[nt], 0, 0, 0);
    }
  }

  __shared__ float sacc[64 * 132];
#pragma unroll
  for (int nt = 0; nt < 8; ++nt)
#pragma unroll
    for (int i = 0; i < 4; ++i)
      sacc[(wv * 16 + quad * 4 + i) * 132 + nt * 16 + lrow] = acc[nt][i];
  __syncthreads();

  const int row = tid >> 2, cs = (tid & 3) * 32;
  const int gr = row0 + row;
  if (gr < Nn) {
    const float om = 1.f - beta;
#pragma unroll
    for (int g = 0; g < 4; ++g) {
      const int c0 = cs + g * 8;
      const u16x8 pv = *(const u16x8*)(pb + (size_t)gr * Hd + c0);
      const u16x8 xv = *(const u16x8*)(x0b + (size_t)gr * Hd + c0);
      const u16x8 hv = *(const u16x8*)(hb + (size_t)gr * Hd + c0);
      float nv[8];
#pragma unroll
      for (int j = 0; j < 8; ++j) {
        const float gemm = sacc[row * 132 + c0 + j];
        const float pj = bf2f(pv[j]);
        const float xj = bf2f(xv[j]);
        const float outv = om * (pj + 0.5f * xj) + beta * gemm;
        nv[j] = fmaxf(bf2f(hv[j]) + outv, 0.f);
      }
      u16x8 ob;
#pragma unroll
      for (int j = 0; j < 8; ++j) ob[j] = f2bf(nv[j]);
      *(u16x8*)(hb + (size_t)gr * Hd + c0) = ob;
    }
  }
}

// ---------------- head (reads bf16 hb) ----------------
__global__ __launch_bounds__(256) void k_head(const unsigned short* __restrict__ hb,
    const float* __restrict__ W2, const float* __restrict__ b2,
    unsigned short* __restrict__ anb, float* __restrict__ p_lc,
    float* __restrict__ out_emb) {
  const int wid = (blockIdx.x * 256 + threadIdx.x) >> 6;
  const int lane = threadIdx.x & 63;
  if (wid >= Bb) return;
  const unsigned short* hr = hb + (size_t)wid * Hd;
  const float v0 = bf2f(hr[lane]), v1 = bf2f(hr[lane + 64]);
  out_emb[wid * Hd + lane] = v0;
  out_emb[wid * Hd + lane + 64] = v1;
  float ss = v0 * v0 + v1 * v1;
#pragma unroll
  for (int off = 32; off > 0; off >>= 1) ss += __shfl_xor(ss, off);
  const float inv = 1.f / fmaxf(sqrtf(ss), 1e-8f);
  anb[wid * Hd + lane] = f2bf(v0 * inv);
  anb[wid * Hd + lane + 64] = f2bf(v1 * inv);
  float l = 0.f;
  if (lane < Cc) {
    for (int k = 0; k < Hd; ++k) l += bf2f(hr[k]) * W2[k * Cc + lane];
    l += b2[lane];
  }
  float lm = (lane < Cc) ? l : -3.0e38f;
#pragma unroll
  for (int off = 32; off > 0; off >>= 1) lm = fmaxf(lm, __shfl_xor(lm, off));
  float ex = (lane < Cc) ? expf(l - lm) : 0.f;
#pragma unroll
  for (int off = 32; off > 0; off >>= 1) ex += __shfl_xor(ex, off);
  const float lse = logf(ex);
  if (lane < Cc) p_lc[wid * Cc + lane] = l - lm - lse;
}

// ---------------- fused sim = an@an^T (bf16 MFMA) with running top-5 ----------
// r5: the wave-level insert body dominated (float val + int idx + tie-break
// ~8 ops/step). Pack (value,index) into ONE sortable u64 key:
//   key = (monotone_uint(val) << 32) | ~idx
// -> each insert step is 1 u64 cmp + 2 cndmask; tie-break (val desc, idx asc)
// is free; butterfly merge halves too. Selection semantics bit-identical.
// (Guard-free full tiles NaN'd in r5/r6 — do not retry.)
#define CH_N  8
#define CH_SZ 1250
#define SB_LD 136
__global__ __launch_bounds__(256, 2) void k_simtopk(const unsigned short* __restrict__ anb,
    float* __restrict__ cval, int* __restrict__ cidx) {
  __shared__ __align__(16) unsigned short sb[64 * SB_LD];
  const int rt = blockIdx.x / CH_N;
  const int chunk = blockIdx.x % CH_N;
  const int row0 = rt * 64;
  const int cbeg = chunk * CH_SZ;
  const int cend = cbeg + CH_SZ;
  const int tid = threadIdx.x;
  const int wv = tid >> 6;
  const int lane = tid & 63;
  const int lrow = lane & 15;
  const int quad = lane >> 4;

  union Frag { uint4 u4; bf16x8 v; };
  bf16x8 afr[4];
  const int ar = row0 + wv * 16 + lrow;
#pragma unroll
  for (int kq = 0; kq < 4; ++kq) {
    Frag f;
    f.u4 = make_uint4(0u, 0u, 0u, 0u);
    if (ar < Bb) f.u4 = *(const uint4*)(anb + (size_t)ar * Hd + kq * 32 + quad * 8);
    afr[kq] = f.v;
  }

  u64 b[4][KT];
#pragma unroll
  for (int r = 0; r < 4; ++r)
#pragma unroll
    for (int t = 0; t < KT; ++t) b[r][t] = 0ULL;
  u64 minthr = 0ULL;   // min over the 4 rows' current 5th-best key

  const int ntile = (CH_SZ + 63) / 64;
  for (int t = 0; t < ntile; ++t) {
    const int c0 = cbeg + t * 64;
    __syncthreads();
    for (int i = tid; i < 1024; i += 256) {
      const int r = i >> 4, ch = i & 15;
      const int gc = c0 + r;
      uint4 v = make_uint4(0u, 0u, 0u, 0u);
      if (gc < cend) v = *(const uint4*)(anb + (size_t)gc * Hd + ch * 8);
      *(uint4*)&sb[r * SB_LD + ch * 8] = v;
    }
    __syncthreads();
#pragma unroll
    for (int sub = 0; sub < 4; ++sub) {
      f32x4 acc = {0.f, 0.f, 0.f, 0.f};
      const int scol = sub * 16 + lrow;
#pragma unroll
      for (int kq = 0; kq < 4; ++kq) {
        bf16x8 bfr = *(const bf16x8*)&sb[scol * SB_LD + kq * 32 + quad * 8];
        acc = __builtin_amdgcn_mfma_f32_16x16x32_bf16(afr[kq], bfr, acc, 0, 0, 0);
      }
      const int gc = c0 + scol;
      const bool ok = gc < cend;
      const unsigned int loi = (unsigned int)(~gc);
      u64 kk[4];
#pragma unroll
      for (int i = 0; i < 4; ++i) {
        const float v = ok ? acc[i] : -3.0e38f;
        kk[i] = ((u64)mkkey(v) << 32) | loi;
      }
      u64 mxk = kk[0] > kk[1] ? kk[0] : kk[1];
      u64 mxk2 = kk[2] > kk[3] ? kk[2] : kk[3];
      mxk = mxk > mxk2 ? mxk : mxk2;
      if (mxk > minthr) {
#pragma unroll
        for (int i = 0; i < 4; ++i) {
          u64 v = kk[i];
          if (v > b[i][KT - 1]) {
#pragma unroll
            for (int s = 0; s < KT; ++s) {
              if (v > b[i][s]) { u64 o = b[i][s]; b[i][s] = v; v = o; }
            }
          }
        }
        u64 m01 = b[0][KT - 1] < b[1][KT - 1] ? b[0][KT - 1] : b[1][KT - 1];
        u64 m23 = b[2][KT - 1] < b[3][KT - 1] ? b[2][KT - 1] : b[3][KT - 1];
        minthr = m01 < m23 ? m01 : m23;
      }
    }
  }

  // In-register butterfly merge across the 16 lanes (lrow) sharing each row.
  // Lists are sorted desc as u64; sequential insertion preserves the invariant.
#pragma unroll
  for (int off = 1; off < 16; off <<= 1) {
#pragma unroll
    for (int i = 0; i < 4; ++i) {
      u64 o[KT];
#pragma unroll
      for (int t = 0; t < KT; ++t) o[t] = __shfl_xor(b[i][t], off);
#pragma unroll
      for (int t = 0; t < KT; ++t) {
        u64 v = o[t];
        if (v > b[i][KT - 1]) {
#pragma unroll
          for (int s = 0; s < KT; ++s) {
            if (v > b[i][s]) { u64 tmp = b[i][s]; b[i][s] = v; v = tmp; }
          }
        }
      }
    }
  }

  if (lrow == 0) {
#pragma unroll
    for (int i = 0; i < 4; ++i) {
      const int gr = row0 + wv * 16 + quad * 4 + i;
      if (gr < Bb) {
#pragma unroll
        for (int t = 0; t < KT; ++t) {
          const unsigned int khi = (unsigned int)(b[i][t] >> 32);
          cval[(size_t)gr * (CH_N * KT) + chunk * KT + t] = unkey(khi);
          cidx[(size_t)gr * (CH_N * KT) + chunk * KT + t] = (int)~(unsigned int)b[i][t];
        }
      }
    }
  }
}

// ---------------- final ----------------
__global__ __launch_bounds__(256) void k_final(const float* __restrict__ cval,
    const int* __restrict__ cidx, const int* __restrict__ y,
    const float* __restrict__ p_lc, float* __restrict__ out_final) {
  const int b = blockIdx.x * 256 + threadIdx.x;
  if (b >= Bb) return;
  float tv5[KT]; int ti5[KT];
#pragma unroll
  for (int t = 0; t < KT; ++t) { tv5[t] = -3.0e38f; ti5[t] = 0x7fffffff; }
  for (int m = 0; m < CH_N * KT; ++m) {
    float v = cval[(size_t)b * (CH_N * KT) + m]; int id = cidx[(size_t)b * (CH_N * KT) + m];
    if (v > tv5[KT - 1] || (v == tv5[KT - 1] && id < ti5[KT - 1])) {
#pragma unroll
      for (int t = 0; t < KT; ++t) {
        if (v > tv5[t] || (v == tv5[t] && id < ti5[t])) {
          float ov = tv5[t]; int oi = ti5[t];
          tv5[t] = v; ti5[t] = id; v = ov; id = oi;
        }
      }
    }
  }
  float w[KT]; int cls[KT];
#pragma unroll
  for (int t = 0; t < KT; ++t) { w[t] = expf(tv5[t]); cls[t] = y[ti5[t]]; }
  float m = -3.0e38f;
  for (int c = 0; c < Cc; ++c) {
    float f = 0.f;
#pragma unroll
    for (int t = 0; t < KT; ++t) f += (cls[t] == c) ? w[t] : 0.f;
    m = fmaxf(m, f);
  }
  float s = 0.f;
  for (int c = 0; c < Cc; ++c) {
    float f = 0.f;
#pragma unroll
    for (int t = 0; t < KT; ++t) f += (cls[t] == c) ? w[t] : 0.f;
    s += expf(f - m);
  }
  const float lse = logf(s);
  for (int c = 0; c < Cc; ++c) {
    float f = 0.f;
#pragma unroll
    for (int t = 0; t < KT; ++t) f += (cls[t] == c) ? w[t] : 0.f;
    out_final[b * Cc + c] = 0.5f * p_lc[b * Cc + c] + 0.5f * (f - m - lse);
  }
}

extern "C" void kernel_launch(void* const* d_in, const int* in_sizes, int n_in,
                              void* d_out, int out_size, void* d_ws, size_t ws_size,
                              hipStream_t stream) {
  const float* x  = (const float*)d_in[0];
  const int* erow = (const int*)d_in[1];
  const int* ecol = erow + En;
  const float* ew = (const float*)d_in[2];
  const int* y    = (const int*)d_in[3];
  const float* W1 = (const float*)d_in[5];
  const float* b1 = (const float*)d_in[6];
  const float* cw1 = (const float*)d_in[7];
  const float* cw2 = (const float*)d_in[8];
  const float* W2 = (const float*)d_in[9];
  const float* b2 = (const float*)d_in[10];
  float* out = (float*)d_out;

  float* ws = (float*)d_ws;
  size_t off = 0;
  float* plc = ws + off; off += (size_t)Bb * Cc;
  float* cval = ws + off; off += (size_t)Bb * (CH_N * KT);
  int* cidx  = (int*)(ws + off); off += (size_t)Bb * (CH_N * KT);
  int* counts = (int*)(ws + off); off += Nn;
  int* fill   = (int*)(ws + off); off += Nn;
  int* rptr   = (int*)(ws + off); off += Nn + 4;
  int2* cpair = (int2*)(ws + off); off += (size_t)2 * En;   // even offset -> 8B aligned
  unsigned short* anb = (unsigned short*)(ws + off); off += (size_t)Bb * Hd / 2;
  unsigned short* hb  = (unsigned short*)(ws + off); off += (size_t)NR * Hd / 2;
  unsigned short* x0b = (unsigned short*)(ws + off); off += (size_t)NR * Hd / 2;
  unsigned short* pb  = (unsigned short*)(ws + off); off += (size_t)NR * Hd / 2;
  unsigned short* W1p = (unsigned short*)(ws + off); off += 65536 / 2;
  unsigned short* Wcp = (unsigned short*)(ws + off); off += 294912 / 2;

  k_pack_w1<<<256, 256, 0, stream>>>(W1, W1p);
  k_pack_wc<<<1152, 256, 0, stream>>>(cw1, cw2, Wcp);
  k_in<<<NR / 64, 256, 0, stream>>>(x, W1p, b1, hb, x0b);
  hipMemsetAsync(counts, 0, (size_t)2 * Nn * sizeof(int), stream);
  k_hist<<<(En + 255) / 256, 256, 0, stream>>>(erow, counts);
  k_scan2<<<(Nn + 255) / 256, 256, 0, stream>>>(counts, rptr);
  k_scatter<<<(En + 255) / 256, 256, 0, stream>>>(erow, ecol, ew, rptr, fill, cpair);
  for (int l = 0; l < Ll; ++l) {
    const float beta = logf(1.0f / (float)(l + 1) + 1.0f);
    k_spmm<<<(Nn * 64 + 255) / 256, 256, 0, stream>>>(rptr, cpair, hb, pb);
    k_layer<<<NR / 64, 256, 0, stream>>>(pb, x0b, Wcp + (size_t)l * 32768, hb, beta);
  }
  k_head<<<(Bb * 64) / 256, 256, 0, stream>>>(hb, W2, b2, anb, plc, out + (size_t)Bb * Cc);
  k_simtopk<<<((Bb + 63) / 64) * CH_N, 256, 0, stream>>>(anb, cval, cidx);
  k_final<<<(Bb + 255) / 256, 256, 0, stream>>>(cval, cidx, y, plc, out);
}

// Round 8
// 999.403 us; speedup vs baseline: 1.2536x; 1.0135x over previous
//
#include <hip/hip_runtime.h>
#include <hip/hip_bf16.h>
#include <math.h>

#define Nn  50000
#define NR  50048   // rows padded to 64
#define En  800000
#define DIN 500
#define Hd  128
#define Cc  40
#define Bb  10000
#define Ll  9
#define KT  5

typedef short bf16x8 __attribute__((ext_vector_type(8)));
typedef unsigned short u16x8 __attribute__((ext_vector_type(8)));
typedef float f32x4 __attribute__((ext_vector_type(4)));

__device__ inline float bf2f(unsigned short u) {
  union { unsigned int i; float f; } c; c.i = (unsigned int)u << 16; return c.f;
}
__device__ inline unsigned short f2bf(float f) {
  __hip_bfloat16 b = __float2bfloat16(f);
  return *(unsigned short*)&b;
}

// ---------------- weight packing into B-fragment layout ----------------
__global__ __launch_bounds__(256) void k_pack_w1(const float* __restrict__ W1,
                                                 unsigned short* __restrict__ W1p) {
  const int id = blockIdx.x * 256 + threadIdx.x;   // 16*4*128*8 = 65536
  if (id >= 65536) return;
  const int j = id & 7, col = (id >> 3) & 127, qk = id >> 10;  // qk = kk*4+quad
  const int k = (qk >> 2) * 32 + (qk & 3) * 8 + j;
  W1p[id] = f2bf((k < DIN) ? W1[(size_t)k * Hd + col] : 0.f);
}

// Wcat[l] = [W1l ; 0.5*W2l]  (K=256), same frag packing, 32768 elems/layer
__global__ __launch_bounds__(256) void k_pack_wc(const float* __restrict__ cw1,
    const float* __restrict__ cw2, unsigned short* __restrict__ Wcp) {
  const int id = blockIdx.x * 256 + threadIdx.x;   // 9*32768 = 294912
  if (id >= 294912) return;
  const int j = id & 7, col = (id >> 3) & 127, qk = (id >> 10) & 31, l = id >> 15;
  const int k = (qk >> 2) * 32 + (qk & 3) * 8 + j;  // 0..255
  float v;
  if (k < 128) v = cw1[((size_t)l * 128 + k) * 128 + col];
  else         v = 0.5f * cw2[((size_t)l * 128 + (k - 128)) * 128 + col];
  Wcp[id] = f2bf(v);
}

// ---------------- input GEMM (MFMA): hb = bf16(relu(x @ W1 + b1)) ----------------
__global__ __launch_bounds__(256) void k_in(const float* __restrict__ x,
    const unsigned short* __restrict__ W1p, const float* __restrict__ b1,
    unsigned short* __restrict__ hb, unsigned short* __restrict__ x0b) {
  const int tid = threadIdx.x;
  const int wv = tid >> 6, lane = tid & 63;
  const int lrow = lane & 15, quad = lane >> 4;
  const int row0 = blockIdx.x * 64;
  const int ar = row0 + wv * 16 + lrow;
  f32x4 acc[8];
#pragma unroll
  for (int t = 0; t < 8; ++t) acc[t] = (f32x4){0.f, 0.f, 0.f, 0.f};

  for (int kk = 0; kk < 16; ++kk) {
    const int kbase = kk * 32 + quad * 8;
    float av[8];
    if (ar < Nn) {
      if (kk < 15) {
        const float4 p0 = *(const float4*)(x + (size_t)ar * DIN + kbase);
        const float4 p1 = *(const float4*)(x + (size_t)ar * DIN + kbase + 4);
        av[0] = p0.x; av[1] = p0.y; av[2] = p0.z; av[3] = p0.w;
        av[4] = p1.x; av[5] = p1.y; av[6] = p1.z; av[7] = p1.w;
      } else {
#pragma unroll
        for (int j = 0; j < 8; ++j)
          av[j] = (kbase + j < DIN) ? x[(size_t)ar * DIN + kbase + j] : 0.f;
      }
    } else {
#pragma unroll
      for (int j = 0; j < 8; ++j) av[j] = 0.f;
    }
    bf16x8 af;
#pragma unroll
    for (int j = 0; j < 8; ++j) af[j] = (short)f2bf(av[j]);
#pragma unroll
    for (int nt = 0; nt < 8; ++nt) {
      const bf16x8 bf = *(const bf16x8*)(W1p + ((size_t)(kk * 4 + quad) * 128 + nt * 16 + lrow) * 8);
      acc[nt] = __builtin_amdgcn_mfma_f32_16x16x32_bf16(af, bf, acc[nt], 0, 0, 0);
    }
  }

  __shared__ float sacc[64 * 132];
#pragma unroll
  for (int nt = 0; nt < 8; ++nt)
#pragma unroll
    for (int i = 0; i < 4; ++i)
      sacc[(wv * 16 + quad * 4 + i) * 132 + nt * 16 + lrow] = acc[nt][i];
  __syncthreads();

  const int row = tid >> 2, cs = (tid & 3) * 32;
  const int gr = row0 + row;
  if (gr < Nn) {
#pragma unroll
    for (int g = 0; g < 4; ++g) {
      const int c0 = cs + g * 8;
      float v[8];
#pragma unroll
      for (int j = 0; j < 8; ++j)
        v[j] = fmaxf(sacc[row * 132 + c0 + j] + b1[c0 + j], 0.f);
      u16x8 ob;
#pragma unroll
      for (int j = 0; j < 8; ++j) ob[j] = f2bf(v[j]);
      *(u16x8*)(hb + (size_t)gr * Hd + c0) = ob;
      *(u16x8*)(x0b + (size_t)gr * Hd + c0) = ob;
    }
  }
}

// ---------------- CSR build ----------------
__global__ void k_hist(const int* __restrict__ rows, int* __restrict__ counts) {
  int e = blockIdx.x * 256 + threadIdx.x;
  if (e < En) atomicAdd(&counts[rows[e]], 1);
}

// Parallel scan: each block redundantly sums its prefix (L2-resident, fully
// parallel) then scans its own 256-element segment.
__global__ __launch_bounds__(256) void k_scan2(const int* __restrict__ counts,
                                               int* __restrict__ rptr) {
  __shared__ int sdata[256];
  const int b = blockIdx.x, tid = threadIdx.x;
  const int npre = b << 8;
  int s0 = 0, s1 = 0, s2 = 0, s3 = 0;
  int i = tid;
  for (; i + 768 < npre; i += 1024) {
    s0 += counts[i]; s1 += counts[i + 256]; s2 += counts[i + 512]; s3 += counts[i + 768];
  }
  for (; i < npre; i += 256) s0 += counts[i];
  sdata[tid] = s0 + s1 + s2 + s3;
  __syncthreads();
  for (int off = 128; off > 0; off >>= 1) {
    if (tid < off) sdata[tid] += sdata[tid + off];
    __syncthreads();
  }
  const int base = sdata[0];
  __syncthreads();
  const int gi = npre + tid;
  int v = (gi < Nn) ? counts[gi] : 0;
  sdata[tid] = v;
  __syncthreads();
  for (int off = 1; off < 256; off <<= 1) {
    int t = (tid >= off) ? sdata[tid - off] : 0;
    __syncthreads();
    sdata[tid] += t;
    __syncthreads();
  }
  if (gi < Nn) rptr[gi + 1] = base + sdata[tid];
  if (b == 0 && tid == 0) rptr[0] = 0;
}

// scatter (col,w) as a single int2 pair: one 8B index load per edge in spmm
__global__ void k_scatter(const int* __restrict__ rows, const int* __restrict__ cols,
                          const float* __restrict__ w, const int* __restrict__ ptr,
                          int* __restrict__ fill, int2* __restrict__ cpair) {
  int e = blockIdx.x * 256 + threadIdx.x;
  if (e >= En) return;
  int r = rows[e];
  int pos = atomicAdd(&fill[r], 1);
  int d = ptr[r] + pos;
  int2 pr; pr.x = cols[e]; pr.y = __float_as_int(w[e]);
  cpair[d] = pr;
}

// ---------------- SpMM: pb = bf16(0.5 * segment_sum(w * hb[col])) --------------
// r4 known-good: one row per wave (50000 independent waves); edges strided
// over 4 lane-groups of 16; uint4 loads; (col,w) one int2.
__global__ __launch_bounds__(256) void k_spmm(const int* __restrict__ ptr,
    const int2* __restrict__ cpair,
    const unsigned short* __restrict__ hb, unsigned short* __restrict__ pb) {
  const int wave = (blockIdx.x * 256 + threadIdx.x) >> 6;
  const int lane = threadIdx.x & 63;
  const int g = lane >> 4;        // edge group 0..3
  const int fl = lane & 15;       // feature lane: feats fl*8 .. fl*8+7
  if (wave >= Nn) return;
  const int s = ptr[wave], e_end = ptr[wave + 1];
  float acc[8];
#pragma unroll
  for (int j = 0; j < 8; ++j) acc[j] = 0.f;

  auto acc8 = [&](uint4 v, float w) {
    union { unsigned int i; float f; } t;
    t.i = v.x << 16;         acc[0] += w * t.f;
    t.i = v.x & 0xFFFF0000u; acc[1] += w * t.f;
    t.i = v.y << 16;         acc[2] += w * t.f;
    t.i = v.y & 0xFFFF0000u; acc[3] += w * t.f;
    t.i = v.z << 16;         acc[4] += w * t.f;
    t.i = v.z & 0xFFFF0000u; acc[5] += w * t.f;
    t.i = v.w << 16;         acc[6] += w * t.f;
    t.i = v.w & 0xFFFF0000u; acc[7] += w * t.f;
  };

  int e = s + g;
  for (; e + 12 < e_end; e += 16) {
    const int2 p0 = cpair[e];
    const int2 p1 = cpair[e + 4];
    const int2 p2 = cpair[e + 8];
    const int2 p3 = cpair[e + 12];
    const uint4 v0 = *(const uint4*)(hb + (size_t)p0.x * Hd + fl * 8);
    const uint4 v1 = *(const uint4*)(hb + (size_t)p1.x * Hd + fl * 8);
    const uint4 v2 = *(const uint4*)(hb + (size_t)p2.x * Hd + fl * 8);
    const uint4 v3 = *(const uint4*)(hb + (size_t)p3.x * Hd + fl * 8);
    acc8(v0, __int_as_float(p0.y)); acc8(v1, __int_as_float(p1.y));
    acc8(v2, __int_as_float(p2.y)); acc8(v3, __int_as_float(p3.y));
  }
  for (; e + 4 < e_end; e += 8) {
    const int2 p0 = cpair[e];
    const int2 p1 = cpair[e + 4];
    const uint4 v0 = *(const uint4*)(hb + (size_t)p0.x * Hd + fl * 8);
    const uint4 v1 = *(const uint4*)(hb + (size_t)p1.x * Hd + fl * 8);
    acc8(v0, __int_as_float(p0.y)); acc8(v1, __int_as_float(p1.y));
  }
  if (e < e_end) {
    const int2 p0 = cpair[e];
    const uint4 v = *(const uint4*)(hb + (size_t)p0.x * Hd + fl * 8);
    acc8(v, __int_as_float(p0.y));
  }
#pragma unroll
  for (int j = 0; j < 8; ++j) acc[j] += __shfl_xor(acc[j], 16);
#pragma unroll
  for (int j = 0; j < 8; ++j) acc[j] += __shfl_xor(acc[j], 32);
  if (g == 0) {
    uint4 o;
    o.x = (unsigned int)f2bf(0.5f * acc[0]) | ((unsigned int)f2bf(0.5f * acc[1]) << 16);
    o.y = (unsigned int)f2bf(0.5f * acc[2]) | ((unsigned int)f2bf(0.5f * acc[3]) << 16);
    o.z = (unsigned int)f2bf(0.5f * acc[4]) | ((unsigned int)f2bf(0.5f * acc[5]) << 16);
    o.w = (unsigned int)f2bf(0.5f * acc[6]) | ((unsigned int)f2bf(0.5f * acc[7]) << 16);
    *(uint4*)(pb + (size_t)wave * Hd + fl * 8) = o;
  }
}

// ---------------- layer (MFMA), residual in bf16 hb (in-place) ----------------
__global__ __launch_bounds__(256) void k_layer(const unsigned short* __restrict__ pb,
    const unsigned short* __restrict__ x0b, const unsigned short* __restrict__ Wcp,
    unsigned short* __restrict__ hb, float beta) {
  const int tid = threadIdx.x;
  const int wv = tid >> 6, lane = tid & 63;
  const int lrow = lane & 15, quad = lane >> 4;
  const int row0 = blockIdx.x * 64;
  const int ar = row0 + wv * 16 + lrow;
  f32x4 acc[8];
#pragma unroll
  for (int t = 0; t < 8; ++t) acc[t] = (f32x4){0.f, 0.f, 0.f, 0.f};

#pragma unroll
  for (int kk = 0; kk < 8; ++kk) {
    const unsigned short* src = (kk < 4) ? pb : x0b;
    const int ko = (kk & 3) * 32 + quad * 8;
    const bf16x8 af = *(const bf16x8*)(src + (size_t)ar * Hd + ko);
#pragma unroll
    for (int nt = 0; nt < 8; ++nt) {
      const bf16x8 bf = *(const bf16x8*)(Wcp + ((size_t)(kk * 4 + quad) * 128 + nt * 16 + lrow) * 8);
      acc[nt] = __builtin_amdgcn_mfma_f32_16x16x32_bf16(af, bf, acc[nt], 0, 0, 0);
    }
  }

  __shared__ float sacc[64 * 132];
#pragma unroll
  for (int nt = 0; nt < 8; ++nt)
#pragma unroll
    for (int i = 0; i < 4; ++i)
      sacc[(wv * 16 + quad * 4 + i) * 132 + nt * 16 + lrow] = acc[nt][i];
  __syncthreads();

  const int row = tid >> 2, cs = (tid & 3) * 32;
  const int gr = row0 + row;
  if (gr < Nn) {
    const float om = 1.f - beta;
#pragma unroll
    for (int g = 0; g < 4; ++g) {
      const int c0 = cs + g * 8;
      const u16x8 pv = *(const u16x8*)(pb + (size_t)gr * Hd + c0);
      const u16x8 xv = *(const u16x8*)(x0b + (size_t)gr * Hd + c0);
      const u16x8 hv = *(const u16x8*)(hb + (size_t)gr * Hd + c0);
      float nv[8];
#pragma unroll
      for (int j = 0; j < 8; ++j) {
        const float gemm = sacc[row * 132 + c0 + j];
        const float pj = bf2f(pv[j]);
        const float xj = bf2f(xv[j]);
        const float outv = om * (pj + 0.5f * xj) + beta * gemm;
        nv[j] = fmaxf(bf2f(hv[j]) + outv, 0.f);
      }
      u16x8 ob;
#pragma unroll
      for (int j = 0; j < 8; ++j) ob[j] = f2bf(nv[j]);
      *(u16x8*)(hb + (size_t)gr * Hd + c0) = ob;
    }
  }
}

// ---------------- head (reads bf16 hb) ----------------
__global__ __launch_bounds__(256) void k_head(const unsigned short* __restrict__ hb,
    const float* __restrict__ W2, const float* __restrict__ b2,
    unsigned short* __restrict__ anb, float* __restrict__ p_lc,
    float* __restrict__ out_emb) {
  const int wid = (blockIdx.x * 256 + threadIdx.x) >> 6;
  const int lane = threadIdx.x & 63;
  if (wid >= Bb) return;
  const unsigned short* hr = hb + (size_t)wid * Hd;
  const float v0 = bf2f(hr[lane]), v1 = bf2f(hr[lane + 64]);
  out_emb[wid * Hd + lane] = v0;
  out_emb[wid * Hd + lane + 64] = v1;
  float ss = v0 * v0 + v1 * v1;
#pragma unroll
  for (int off = 32; off > 0; off >>= 1) ss += __shfl_xor(ss, off);
  const float inv = 1.f / fmaxf(sqrtf(ss), 1e-8f);
  anb[wid * Hd + lane] = f2bf(v0 * inv);
  anb[wid * Hd + lane + 64] = f2bf(v1 * inv);
  float l = 0.f;
  if (lane < Cc) {
    for (int k = 0; k < Hd; ++k) l += bf2f(hr[k]) * W2[k * Cc + lane];
    l += b2[lane];
  }
  float lm = (lane < Cc) ? l : -3.0e38f;
#pragma unroll
  for (int off = 32; off > 0; off >>= 1) lm = fmaxf(lm, __shfl_xor(lm, off));
  float ex = (lane < Cc) ? expf(l - lm) : 0.f;
#pragma unroll
  for (int off = 32; off > 0; off >>= 1) ex += __shfl_xor(ex, off);
  const float lse = logf(ex);
  if (lane < Cc) p_lc[wid * Cc + lane] = l - lm - lse;
}

// ---------------- fused sim = an@an^T (bf16 MFMA) with running top-5 ----------
// r7 post-mortem: u64 keys regressed (AGPR shuffling + longer dep chains;
// VALUBusy fell 87->71 yet dur rose). Reverted to the r4 float/int insert.
// Series evidence: CH_N=4 beats 8 on per-block fixed cost (r0 145 vs r4 150);
// butterfly beats LDS merge (r4 150 vs r1 156). This round = CH_N=4 +
// butterfly + per-i ballot gate (body i covers rows {i,4+i,8+i,12+i}; skipped
// iff all four fail, P~0.24 steady-state -> ~25% insert-work cut).
// (Guard-free full tiles NaN'd in r5/r6 — do not retry. u64 keys: do not retry.)
#define CH_N  4
#define CH_SZ 2500
#define SB_LD 136
__global__ __launch_bounds__(256, 2) void k_simtopk(const unsigned short* __restrict__ anb,
    float* __restrict__ cval, int* __restrict__ cidx) {
  __shared__ __align__(16) unsigned short sb[64 * SB_LD];
  const int rt = blockIdx.x / CH_N;
  const int chunk = blockIdx.x % CH_N;
  const int row0 = rt * 64;
  const int cbeg = chunk * CH_SZ;
  const int cend = cbeg + CH_SZ;
  const int tid = threadIdx.x;
  const int wv = tid >> 6;
  const int lane = tid & 63;
  const int lrow = lane & 15;
  const int quad = lane >> 4;

  union Frag { uint4 u4; bf16x8 v; };
  bf16x8 afr[4];
  const int ar = row0 + wv * 16 + lrow;
#pragma unroll
  for (int kq = 0; kq < 4; ++kq) {
    Frag f;
    f.u4 = make_uint4(0u, 0u, 0u, 0u);
    if (ar < Bb) f.u4 = *(const uint4*)(anb + (size_t)ar * Hd + kq * 32 + quad * 8);
    afr[kq] = f.v;
  }

  float bv[4][KT];
  int bi[4][KT];
#pragma unroll
  for (int r = 0; r < 4; ++r)
#pragma unroll
    for (int t = 0; t < KT; ++t) { bv[r][t] = -3.0e38f; bi[r][t] = 0x7fffffff; }

  const int ntile = (CH_SZ + 63) / 64;
  for (int t = 0; t < ntile; ++t) {
    const int c0 = cbeg + t * 64;
    __syncthreads();
    for (int i = tid; i < 1024; i += 256) {
      const int r = i >> 4, ch = i & 15;
      const int gc = c0 + r;
      uint4 v = make_uint4(0u, 0u, 0u, 0u);
      if (gc < cend) v = *(const uint4*)(anb + (size_t)gc * Hd + ch * 8);
      *(uint4*)&sb[r * SB_LD + ch * 8] = v;
    }
    __syncthreads();
#pragma unroll
    for (int sub = 0; sub < 4; ++sub) {
      f32x4 acc = {0.f, 0.f, 0.f, 0.f};
      const int scol = sub * 16 + lrow;
#pragma unroll
      for (int kq = 0; kq < 4; ++kq) {
        bf16x8 bfr = *(const bf16x8*)&sb[scol * SB_LD + kq * 32 + quad * 8];
        acc = __builtin_amdgcn_mfma_f32_16x16x32_bf16(afr[kq], bfr, acc, 0, 0, 0);
      }
      const int gc = c0 + scol;
      const bool ok = gc < cend;
#pragma unroll
      for (int i = 0; i < 4; ++i) {
        const float v = ok ? acc[i] : -3.0e38f;
        // wave votes for body i across all quads (= rows i,4+i,8+i,12+i);
        // s_cbranch_execz skips the whole body only when every lane fails.
        if (__ballot(v > bv[i][KT - 1])) {
          if (v > bv[i][KT - 1]) {
            float tv = v; int ti = gc;
#pragma unroll
            for (int s = 0; s < KT; ++s) {
              if (tv > bv[i][s]) {
                float ov = bv[i][s]; int oi = bi[i][s];
                bv[i][s] = tv; bi[i][s] = ti; tv = ov; ti = oi;
              }
            }
          }
        }
      }
    }
  }

  // In-register butterfly merge across the 16 lanes (lrow) sharing each row.
  // Lists sorted desc, ties index-asc; sequential insertion preserves it.
#pragma unroll
  for (int off = 1; off < 16; off <<= 1) {
#pragma unroll
    for (int i = 0; i < 4; ++i) {
      float ov[KT]; int oi[KT];
#pragma unroll
      for (int t = 0; t < KT; ++t) {
        ov[t] = __shfl_xor(bv[i][t], off);
        oi[t] = __shfl_xor(bi[i][t], off);
      }
#pragma unroll
      for (int t = 0; t < KT; ++t) {
        float v = ov[t]; int id = oi[t];
        if (v > bv[i][KT - 1] || (v == bv[i][KT - 1] && id < bi[i][KT - 1])) {
#pragma unroll
          for (int s = 0; s < KT; ++s) {
            const bool take = (v > bv[i][s]) || (v == bv[i][s] && id < bi[i][s]);
            if (take) {
              float tv = bv[i][s]; int ti = bi[i][s];
              bv[i][s] = v; bi[i][s] = id; v = tv; id = ti;
            }
          }
        }
      }
    }
  }

  if (lrow == 0) {
#pragma unroll
    for (int i = 0; i < 4; ++i) {
      const int gr = row0 + wv * 16 + quad * 4 + i;
      if (gr < Bb) {
#pragma unroll
        for (int t = 0; t < KT; ++t) {
          cval[(size_t)gr * (CH_N * KT) + chunk * KT + t] = bv[i][t];
          cidx[(size_t)gr * (CH_N * KT) + chunk * KT + t] = bi[i][t];
        }
      }
    }
  }
}

// ---------------- final ----------------
__global__ __launch_bounds__(256) void k_final(const float* __restrict__ cval,
    const int* __restrict__ cidx, const int* __restrict__ y,
    const float* __restrict__ p_lc, float* __restrict__ out_final) {
  const int b = blockIdx.x * 256 + threadIdx.x;
  if (b >= Bb) return;
  float tv5[KT]; int ti5[KT];
#pragma unroll
  for (int t = 0; t < KT; ++t) { tv5[t] = -3.0e38f; ti5[t] = 0x7fffffff; }
  for (int m = 0; m < CH_N * KT; ++m) {
    float v = cval[(size_t)b * (CH_N * KT) + m]; int id = cidx[(size_t)b * (CH_N * KT) + m];
    if (v > tv5[KT - 1] || (v == tv5[KT - 1] && id < ti5[KT - 1])) {
#pragma unroll
      for (int t = 0; t < KT; ++t) {
        if (v > tv5[t] || (v == tv5[t] && id < ti5[t])) {
          float ov = tv5[t]; int oi = ti5[t];
          tv5[t] = v; ti5[t] = id; v = ov; id = oi;
        }
      }
    }
  }
  float w[KT]; int cls[KT];
#pragma unroll
  for (int t = 0; t < KT; ++t) { w[t] = expf(tv5[t]); cls[t] = y[ti5[t]]; }
  float m = -3.0e38f;
  for (int c = 0; c < Cc; ++c) {
    float f = 0.f;
#pragma unroll
    for (int t = 0; t < KT; ++t) f += (cls[t] == c) ? w[t] : 0.f;
    m = fmaxf(m, f);
  }
  float s = 0.f;
  for (int c = 0; c < Cc; ++c) {
    float f = 0.f;
#pragma unroll
    for (int t = 0; t < KT; ++t) f += (cls[t] == c) ? w[t] : 0.f;
    s += expf(f - m);
  }
  const float lse = logf(s);
  for (int c = 0; c < Cc; ++c) {
    float f = 0.f;
#pragma unroll
    for (int t = 0; t < KT; ++t) f += (cls[t] == c) ? w[t] : 0.f;
    out_final[b * Cc + c] = 0.5f * p_lc[b * Cc + c] + 0.5f * (f - m - lse);
  }
}

extern "C" void kernel_launch(void* const* d_in, const int* in_sizes, int n_in,
                              void* d_out, int out_size, void* d_ws, size_t ws_size,
                              hipStream_t stream) {
  const float* x  = (const float*)d_in[0];
  const int* erow = (const int*)d_in[1];
  const int* ecol = erow + En;
  const float* ew = (const float*)d_in[2];
  const int* y    = (const int*)d_in[3];
  const float* W1 = (const float*)d_in[5];
  const float* b1 = (const float*)d_in[6];
  const float* cw1 = (const float*)d_in[7];
  const float* cw2 = (const float*)d_in[8];
  const float* W2 = (const float*)d_in[9];
  const float* b2 = (const float*)d_in[10];
  float* out = (float*)d_out;

  float* ws = (float*)d_ws;
  size_t off = 0;
  float* plc = ws + off; off += (size_t)Bb * Cc;
  float* cval = ws + off; off += (size_t)Bb * (CH_N * KT);
  int* cidx  = (int*)(ws + off); off += (size_t)Bb * (CH_N * KT);
  int* counts = (int*)(ws + off); off += Nn;
  int* fill   = (int*)(ws + off); off += Nn;
  int* rptr   = (int*)(ws + off); off += Nn + 4;
  int2* cpair = (int2*)(ws + off); off += (size_t)2 * En;   // even offset -> 8B aligned
  unsigned short* anb = (unsigned short*)(ws + off); off += (size_t)Bb * Hd / 2;
  unsigned short* hb  = (unsigned short*)(ws + off); off += (size_t)NR * Hd / 2;
  unsigned short* x0b = (unsigned short*)(ws + off); off += (size_t)NR * Hd / 2;
  unsigned short* pb  = (unsigned short*)(ws + off); off += (size_t)NR * Hd / 2;
  unsigned short* W1p = (unsigned short*)(ws + off); off += 65536 / 2;
  unsigned short* Wcp = (unsigned short*)(ws + off); off += 294912 / 2;

  k_pack_w1<<<256, 256, 0, stream>>>(W1, W1p);
  k_pack_wc<<<1152, 256, 0, stream>>>(cw1, cw2, Wcp);
  k_in<<<NR / 64, 256, 0, stream>>>(x, W1p, b1, hb, x0b);
  hipMemsetAsync(counts, 0, (size_t)2 * Nn * sizeof(int), stream);
  k_hist<<<(En + 255) / 256, 256, 0, stream>>>(erow, counts);
  k_scan2<<<(Nn + 255) / 256, 256, 0, stream>>>(counts, rptr);
  k_scatter<<<(En + 255) / 256, 256, 0, stream>>>(erow, ecol, ew, rptr, fill, cpair);
  for (int l = 0; l < Ll; ++l) {
    const float beta = logf(1.0f / (float)(l + 1) + 1.0f);
    k_spmm<<<(Nn * 64 + 255) / 256, 256, 0, stream>>>(rptr, cpair, hb, pb);
    k_layer<<<NR / 64, 256, 0, stream>>>(pb, x0b, Wcp + (size_t)l * 32768, hb, beta);
  }
  k_head<<<(Bb * 64) / 256, 256, 0, stream>>>(hb, W2, b2, anb, plc, out + (size_t)Bb * Cc);
  k_simtopk<<<((Bb + 63) / 64) * CH_N, 256, 0, stream>>>(anb, cval, cidx);
  k_final<<<(Bb + 255) / 256, 256, 0, stream>>>(cval, cidx, y, plc, out);
}

// Round 10
// 972.801 us; speedup vs baseline: 1.2879x; 1.0273x over previous
//
#include <hip/hip_runtime.h>
#include <hip/hip_bf16.h>
#include <math.h>

#define Nn  50000
#define NR  50048   // rows padded to 64
#define En  800000
#define DIN 500
#define Hd  128
#define Cc  40
#define Bb  10000
#define Ll  9
#define KT  5

typedef short bf16x8 __attribute__((ext_vector_type(8)));
typedef unsigned short u16x8 __attribute__((ext_vector_type(8)));
typedef float f32x4 __attribute__((ext_vector_type(4)));

__device__ inline float bf2f(unsigned short u) {
  union { unsigned int i; float f; } c; c.i = (unsigned int)u << 16; return c.f;
}
__device__ inline unsigned short f2bf(float f) {
  __hip_bfloat16 b = __float2bfloat16(f);
  return *(unsigned short*)&b;
}

// ---------------- weight packing into B-fragment layout ----------------
__global__ __launch_bounds__(256) void k_pack_w1(const float* __restrict__ W1,
                                                 unsigned short* __restrict__ W1p) {
  const int id = blockIdx.x * 256 + threadIdx.x;   // 16*4*128*8 = 65536
  if (id >= 65536) return;
  const int j = id & 7, col = (id >> 3) & 127, qk = id >> 10;  // qk = kk*4+quad
  const int k = (qk >> 2) * 32 + (qk & 3) * 8 + j;
  W1p[id] = f2bf((k < DIN) ? W1[(size_t)k * Hd + col] : 0.f);
}

// Wcat[l] = [W1l ; 0.5*W2l]  (K=256), same frag packing, 32768 elems/layer
__global__ __launch_bounds__(256) void k_pack_wc(const float* __restrict__ cw1,
    const float* __restrict__ cw2, unsigned short* __restrict__ Wcp) {
  const int id = blockIdx.x * 256 + threadIdx.x;   // 9*32768 = 294912
  if (id >= 294912) return;
  const int j = id & 7, col = (id >> 3) & 127, qk = (id >> 10) & 31, l = id >> 15;
  const int k = (qk >> 2) * 32 + (qk & 3) * 8 + j;  // 0..255
  float v;
  if (k < 128) v = cw1[((size_t)l * 128 + k) * 128 + col];
  else         v = 0.5f * cw2[((size_t)l * 128 + (k - 128)) * 128 + col];
  Wcp[id] = f2bf(v);
}

// ---------------- input GEMM (MFMA): hb = bf16(relu(x @ W1 + b1)) ----------------
__global__ __launch_bounds__(256) void k_in(const float* __restrict__ x,
    const unsigned short* __restrict__ W1p, const float* __restrict__ b1,
    unsigned short* __restrict__ hb, unsigned short* __restrict__ x0b) {
  const int tid = threadIdx.x;
  const int wv = tid >> 6, lane = tid & 63;
  const int lrow = lane & 15, quad = lane >> 4;
  const int row0 = blockIdx.x * 64;
  const int ar = row0 + wv * 16 + lrow;
  f32x4 acc[8];
#pragma unroll
  for (int t = 0; t < 8; ++t) acc[t] = (f32x4){0.f, 0.f, 0.f, 0.f};

  for (int kk = 0; kk < 16; ++kk) {
    const int kbase = kk * 32 + quad * 8;
    float av[8];
    if (ar < Nn) {
      if (kk < 15) {
        const float4 p0 = *(const float4*)(x + (size_t)ar * DIN + kbase);
        const float4 p1 = *(const float4*)(x + (size_t)ar * DIN + kbase + 4);
        av[0] = p0.x; av[1] = p0.y; av[2] = p0.z; av[3] = p0.w;
        av[4] = p1.x; av[5] = p1.y; av[6] = p1.z; av[7] = p1.w;
      } else {
#pragma unroll
        for (int j = 0; j < 8; ++j)
          av[j] = (kbase + j < DIN) ? x[(size_t)ar * DIN + kbase + j] : 0.f;
      }
    } else {
#pragma unroll
      for (int j = 0; j < 8; ++j) av[j] = 0.f;
    }
    bf16x8 af;
#pragma unroll
    for (int j = 0; j < 8; ++j) af[j] = (short)f2bf(av[j]);
#pragma unroll
    for (int nt = 0; nt < 8; ++nt) {
      const bf16x8 bf = *(const bf16x8*)(W1p + ((size_t)(kk * 4 + quad) * 128 + nt * 16 + lrow) * 8);
      acc[nt] = __builtin_amdgcn_mfma_f32_16x16x32_bf16(af, bf, acc[nt], 0, 0, 0);
    }
  }

  __shared__ float sacc[64 * 132];
#pragma unroll
  for (int nt = 0; nt < 8; ++nt)
#pragma unroll
    for (int i = 0; i < 4; ++i)
      sacc[(wv * 16 + quad * 4 + i) * 132 + nt * 16 + lrow] = acc[nt][i];
  __syncthreads();

  const int row = tid >> 2, cs = (tid & 3) * 32;
  const int gr = row0 + row;
  if (gr < Nn) {
#pragma unroll
    for (int g = 0; g < 4; ++g) {
      const int c0 = cs + g * 8;
      float v[8];
#pragma unroll
      for (int j = 0; j < 8; ++j)
        v[j] = fmaxf(sacc[row * 132 + c0 + j] + b1[c0 + j], 0.f);
      u16x8 ob;
#pragma unroll
      for (int j = 0; j < 8; ++j) ob[j] = f2bf(v[j]);
      *(u16x8*)(hb + (size_t)gr * Hd + c0) = ob;
      *(u16x8*)(x0b + (size_t)gr * Hd + c0) = ob;
    }
  }
}

// ---------------- CSR build ----------------
__global__ void k_hist(const int* __restrict__ rows, int* __restrict__ counts) {
  int e = blockIdx.x * 256 + threadIdx.x;
  if (e < En) atomicAdd(&counts[rows[e]], 1);
}

// Parallel scan: each block redundantly sums its prefix (L2-resident, fully
// parallel) then scans its own 256-element segment.
__global__ __launch_bounds__(256) void k_scan2(const int* __restrict__ counts,
                                               int* __restrict__ rptr) {
  __shared__ int sdata[256];
  const int b = blockIdx.x, tid = threadIdx.x;
  const int npre = b << 8;
  int s0 = 0, s1 = 0, s2 = 0, s3 = 0;
  int i = tid;
  for (; i + 768 < npre; i += 1024) {
    s0 += counts[i]; s1 += counts[i + 256]; s2 += counts[i + 512]; s3 += counts[i + 768];
  }
  for (; i < npre; i += 256) s0 += counts[i];
  sdata[tid] = s0 + s1 + s2 + s3;
  __syncthreads();
  for (int off = 128; off > 0; off >>= 1) {
    if (tid < off) sdata[tid] += sdata[tid + off];
    __syncthreads();
  }
  const int base = sdata[0];
  __syncthreads();
  const int gi = npre + tid;
  int v = (gi < Nn) ? counts[gi] : 0;
  sdata[tid] = v;
  __syncthreads();
  for (int off = 1; off < 256; off <<= 1) {
    int t = (tid >= off) ? sdata[tid - off] : 0;
    __syncthreads();
    sdata[tid] += t;
    __syncthreads();
  }
  if (gi < Nn) rptr[gi + 1] = base + sdata[tid];
  if (b == 0 && tid == 0) rptr[0] = 0;
}

// scatter (col,w) as a single int2 pair: one 8B index load per edge
__global__ void k_scatter(const int* __restrict__ rows, const int* __restrict__ cols,
                          const float* __restrict__ w, const int* __restrict__ ptr,
                          int* __restrict__ fill, int2* __restrict__ cpair) {
  int e = blockIdx.x * 256 + threadIdx.x;
  if (e >= En) return;
  int r = rows[e];
  int pos = atomicAdd(&fill[r], 1);
  int d = ptr[r] + pos;
  int2 pr; pr.x = cols[e]; pr.y = __float_as_int(w[e]);
  cpair[d] = pr;
}

// ---------------- FUSED spmm + layer, v2 (parallel gather) ----------------
// r5's fusion failed because each wave serially walked 16 rows (16x latency
// chain). v2: 1024-thread block, 16 waves, each wave owns 4 rows as parallel
// 16-lane groups (row = 16 lanes x 8 feats, x4 edge unroll) -> 16 gathers in
// flight per wave, same as the standalone spmm; 2 blocks/CU x 16 waves keeps
// ~512 in-flight gathers/CU. No cross-lane reduce (groups own rows). Phase B
// consumes the pb tile from LDS (A-frags kk<4 + epilogue pj). Removes the pb
// global round-trip and 9 launches. hb double-buffered (hbr read, hbw write).
#define PB_LD 136
__global__ __launch_bounds__(1024, 8) void k_fused2(const int* __restrict__ ptr,
    const int2* __restrict__ cpair, const unsigned short* __restrict__ hbr,
    const unsigned short* __restrict__ x0b, const unsigned short* __restrict__ Wcp,
    unsigned short* __restrict__ hbw, float beta) {
  __shared__ __align__(16) unsigned short pb_s[64 * PB_LD];
  __shared__ float sacc[64 * 132];
  const int tid = threadIdx.x;
  const int wv = tid >> 6;          // 0..15
  const int lane = tid & 63;
  const int grp = lane >> 4;        // row group 0..3 within wave
  const int gl = lane & 15;         // feature lane: feats gl*8..gl*8+7
  const int row0 = blockIdx.x * 64;
  const int lr = wv * 4 + grp;      // local row 0..63
  const int row = row0 + lr;

  // ---- phase A: gather (one row per 16-lane group, all rows in parallel)
  float acc[8];
#pragma unroll
  for (int j = 0; j < 8; ++j) acc[j] = 0.f;

  auto acc8 = [&](uint4 v, float w) {
    union { unsigned int i; float f; } t;
    t.i = v.x << 16;         acc[0] += w * t.f;
    t.i = v.x & 0xFFFF0000u; acc[1] += w * t.f;
    t.i = v.y << 16;         acc[2] += w * t.f;
    t.i = v.y & 0xFFFF0000u; acc[3] += w * t.f;
    t.i = v.z << 16;         acc[4] += w * t.f;
    t.i = v.z & 0xFFFF0000u; acc[5] += w * t.f;
    t.i = v.w << 16;         acc[6] += w * t.f;
    t.i = v.w & 0xFFFF0000u; acc[7] += w * t.f;
  };

  if (row < Nn) {
    const int s = ptr[row], e_end = ptr[row + 1];
    int e = s;
    for (; e + 3 < e_end; e += 4) {
      const int2 p0 = cpair[e];
      const int2 p1 = cpair[e + 1];
      const int2 p2 = cpair[e + 2];
      const int2 p3 = cpair[e + 3];
      const uint4 v0 = *(const uint4*)(hbr + (size_t)p0.x * Hd + gl * 8);
      const uint4 v1 = *(const uint4*)(hbr + (size_t)p1.x * Hd + gl * 8);
      const uint4 v2 = *(const uint4*)(hbr + (size_t)p2.x * Hd + gl * 8);
      const uint4 v3 = *(const uint4*)(hbr + (size_t)p3.x * Hd + gl * 8);
      acc8(v0, __int_as_float(p0.y)); acc8(v1, __int_as_float(p1.y));
      acc8(v2, __int_as_float(p2.y)); acc8(v3, __int_as_float(p3.y));
    }
    for (; e < e_end; ++e) {
      const int2 p0 = cpair[e];
      const uint4 v = *(const uint4*)(hbr + (size_t)p0.x * Hd + gl * 8);
      acc8(v, __int_as_float(p0.y));
    }
  }
  {
    uint4 o;
    o.x = (unsigned int)f2bf(0.5f * acc[0]) | ((unsigned int)f2bf(0.5f * acc[1]) << 16);
    o.y = (unsigned int)f2bf(0.5f * acc[2]) | ((unsigned int)f2bf(0.5f * acc[3]) << 16);
    o.z = (unsigned int)f2bf(0.5f * acc[4]) | ((unsigned int)f2bf(0.5f * acc[5]) << 16);
    o.w = (unsigned int)f2bf(0.5f * acc[6]) | ((unsigned int)f2bf(0.5f * acc[7]) << 16);
    *(uint4*)&pb_s[lr * PB_LD + gl * 8] = o;
  }
  __syncthreads();

  // ---- phase B: 64x128 layer GEMM; 4 row-frags x 8 col-frags = 32 tiles,
  // 16 waves x 2 tiles. wave wv: rf = wv>>2, cf = (wv&3)*2 + {0,1}.
  const int lrow = lane & 15, quad = lane >> 4;
  const int rf = wv >> 2;
  const int cf0 = (wv & 3) * 2;
  const int arl = rf * 16 + lrow;
  const int ar = row0 + arl;
  f32x4 gacc[2];
  gacc[0] = (f32x4){0.f, 0.f, 0.f, 0.f};
  gacc[1] = (f32x4){0.f, 0.f, 0.f, 0.f};
#pragma unroll
  for (int kk = 0; kk < 8; ++kk) {
    const int ko = (kk & 3) * 32 + quad * 8;
    bf16x8 af;
    if (kk < 4) af = *(const bf16x8*)&pb_s[arl * PB_LD + ko];
    else        af = *(const bf16x8*)(x0b + (size_t)ar * Hd + ko);
#pragma unroll
    for (int t = 0; t < 2; ++t) {
      const bf16x8 bf = *(const bf16x8*)(Wcp + ((size_t)(kk * 4 + quad) * 128 + (cf0 + t) * 16 + lrow) * 8);
      gacc[t] = __builtin_amdgcn_mfma_f32_16x16x32_bf16(af, bf, gacc[t], 0, 0, 0);
    }
  }
#pragma unroll
  for (int t = 0; t < 2; ++t)
#pragma unroll
    for (int i = 0; i < 4; ++i)
      sacc[(rf * 16 + quad * 4 + i) * 132 + (cf0 + t) * 16 + lrow] = gacc[t][i];
  __syncthreads();

  // ---- epilogue: 1024 threads, 8 outputs each
  const int erow = tid >> 4, cs = (tid & 15) * 8;
  const int gr = row0 + erow;
  if (gr < Nn) {
    const float om = 1.f - beta;
    const u16x8 pv = *(const u16x8*)&pb_s[erow * PB_LD + cs];
    const u16x8 xv = *(const u16x8*)(x0b + (size_t)gr * Hd + cs);
    const u16x8 hv = *(const u16x8*)(hbr + (size_t)gr * Hd + cs);
    float nv[8];
#pragma unroll
    for (int j = 0; j < 8; ++j) {
      const float gemm = sacc[erow * 132 + cs + j];
      const float pj = bf2f(pv[j]);
      const float xj = bf2f(xv[j]);
      const float outv = om * (pj + 0.5f * xj) + beta * gemm;
      nv[j] = fmaxf(bf2f(hv[j]) + outv, 0.f);
    }
    u16x8 ob;
#pragma unroll
    for (int j = 0; j < 8; ++j) ob[j] = f2bf(nv[j]);
    *(u16x8*)(hbw + (size_t)gr * Hd + cs) = ob;
  }
}

// ---------------- head (reads bf16 hb) ----------------
__global__ __launch_bounds__(256) void k_head(const unsigned short* __restrict__ hb,
    const float* __restrict__ W2, const float* __restrict__ b2,
    unsigned short* __restrict__ anb, float* __restrict__ p_lc,
    float* __restrict__ out_emb) {
  const int wid = (blockIdx.x * 256 + threadIdx.x) >> 6;
  const int lane = threadIdx.x & 63;
  if (wid >= Bb) return;
  const unsigned short* hr = hb + (size_t)wid * Hd;
  const float v0 = bf2f(hr[lane]), v1 = bf2f(hr[lane + 64]);
  out_emb[wid * Hd + lane] = v0;
  out_emb[wid * Hd + lane + 64] = v1;
  float ss = v0 * v0 + v1 * v1;
#pragma unroll
  for (int off = 32; off > 0; off >>= 1) ss += __shfl_xor(ss, off);
  const float inv = 1.f / fmaxf(sqrtf(ss), 1e-8f);
  anb[wid * Hd + lane] = f2bf(v0 * inv);
  anb[wid * Hd + lane + 64] = f2bf(v1 * inv);
  float l = 0.f;
  if (lane < Cc) {
    for (int k = 0; k < Hd; ++k) l += bf2f(hr[k]) * W2[k * Cc + lane];
    l += b2[lane];
  }
  float lm = (lane < Cc) ? l : -3.0e38f;
#pragma unroll
  for (int off = 32; off > 0; off >>= 1) lm = fmaxf(lm, __shfl_xor(lm, off));
  float ex = (lane < Cc) ? expf(l - lm) : 0.f;
#pragma unroll
  for (int off = 32; off > 0; off >>= 1) ex += __shfl_xor(ex, off);
  const float lse = logf(ex);
  if (lane < Cc) p_lc[wid * Cc + lane] = l - lm - lse;
}

// ---------------- fused sim = an@an^T (bf16 MFMA) with running top-5 ----------
// FROZEN at the r0 structure (145.7 us measured — best of 6 variants tried
// across r1-r8; all "improvements" regressed: minthr gate, CH_N 8/16, u64
// keys, ballot gate, butterfly merge all equal-or-worse). Do not touch.
#define CH_N  4
#define CH_SZ 2500
#define SB_LD 136
__global__ __launch_bounds__(256) void k_simtopk(const unsigned short* __restrict__ anb,
    float* __restrict__ cval, int* __restrict__ cidx) {
  __shared__ __align__(16) char smem[40960];
  unsigned short* sb = (unsigned short*)smem;
  const int rt = blockIdx.x / CH_N;
  const int chunk = blockIdx.x % CH_N;
  const int row0 = rt * 64;
  const int cbeg = chunk * CH_SZ;
  const int cend = cbeg + CH_SZ;
  const int tid = threadIdx.x;
  const int wv = tid >> 6;
  const int lane = tid & 63;
  const int lrow = lane & 15;
  const int quad = lane >> 4;

  union Frag { uint4 u4; bf16x8 v; };
  bf16x8 afr[4];
  const int ar = row0 + wv * 16 + lrow;
#pragma unroll
  for (int kq = 0; kq < 4; ++kq) {
    Frag f;
    f.u4 = make_uint4(0u, 0u, 0u, 0u);
    if (ar < Bb) f.u4 = *(const uint4*)(anb + (size_t)ar * Hd + kq * 32 + quad * 8);
    afr[kq] = f.v;
  }

  float bv[4][KT];
  int bi[4][KT];
#pragma unroll
  for (int r = 0; r < 4; ++r)
#pragma unroll
    for (int t = 0; t < KT; ++t) { bv[r][t] = -3.0e38f; bi[r][t] = 0x7fffffff; }

  const int ntile = (CH_SZ + 63) / 64;
  for (int t = 0; t < ntile; ++t) {
    const int c0 = cbeg + t * 64;
    __syncthreads();
    for (int i = tid; i < 1024; i += 256) {
      const int r = i >> 4, ch = i & 15;
      const int gc = c0 + r;
      uint4 v = make_uint4(0u, 0u, 0u, 0u);
      if (gc < cend) v = *(const uint4*)(anb + (size_t)gc * Hd + ch * 8);
      *(uint4*)&sb[r * SB_LD + ch * 8] = v;
    }
    __syncthreads();
#pragma unroll
    for (int sub = 0; sub < 4; ++sub) {
      f32x4 acc = {0.f, 0.f, 0.f, 0.f};
      const int scol = sub * 16 + lrow;
#pragma unroll
      for (int kq = 0; kq < 4; ++kq) {
        bf16x8 bfr = *(const bf16x8*)&sb[scol * SB_LD + kq * 32 + quad * 8];
        acc = __builtin_amdgcn_mfma_f32_16x16x32_bf16(afr[kq], bfr, acc, 0, 0, 0);
      }
      const int gc = c0 + scol;
      const bool ok = gc < cend;
#pragma unroll
      for (int i = 0; i < 4; ++i) {
        const float v = ok ? acc[i] : -3.0e38f;
        if (v > bv[i][KT - 1]) {
          float tv = v; int ti = gc;
#pragma unroll
          for (int s = 0; s < KT; ++s) {
            if (tv > bv[i][s]) {
              float ov = bv[i][s]; int oi = bi[i][s];
              bv[i][s] = tv; bi[i][s] = ti; tv = ov; ti = oi;
            }
          }
        }
      }
    }
  }

  __syncthreads();
  float* mv = (float*)smem;
  int* mi = (int*)(smem + 20480);
#pragma unroll
  for (int i = 0; i < 4; ++i) {
    const int row = wv * 16 + quad * 4 + i;
#pragma unroll
    for (int t = 0; t < KT; ++t) {
      mv[row * 80 + lrow * KT + t] = bv[i][t];
      mi[row * 80 + lrow * KT + t] = bi[i][t];
    }
  }
  __syncthreads();
  if (tid < 64) {
    const int gr = row0 + tid;
    if (gr < Bb) {
      float tv5[KT]; int ti5[KT];
#pragma unroll
      for (int t = 0; t < KT; ++t) { tv5[t] = -3.0e38f; ti5[t] = 0x7fffffff; }
      for (int m = 0; m < 80; ++m) {
        float v = mv[tid * 80 + m]; int id = mi[tid * 80 + m];
        if (v > tv5[KT - 1] || (v == tv5[KT - 1] && id < ti5[KT - 1])) {
#pragma unroll
          for (int s = 0; s < KT; ++s) {
            if (v > tv5[s] || (v == tv5[s] && id < ti5[s])) {
              float ov = tv5[s]; int oi = ti5[s];
              tv5[s] = v; ti5[s] = id; v = ov; id = oi;
            }
          }
        }
      }
#pragma unroll
      for (int t = 0; t < KT; ++t) {
        cval[gr * (CH_N * KT) + chunk * KT + t] = tv5[t];
        cidx[gr * (CH_N * KT) + chunk * KT + t] = ti5[t];
      }
    }
  }
}

// ---------------- final ----------------
__global__ __launch_bounds__(256) void k_final(const float* __restrict__ cval,
    const int* __restrict__ cidx, const int* __restrict__ y,
    const float* __restrict__ p_lc, float* __restrict__ out_final) {
  const int b = blockIdx.x * 256 + threadIdx.x;
  if (b >= Bb) return;
  float tv5[KT]; int ti5[KT];
#pragma unroll
  for (int t = 0; t < KT; ++t) { tv5[t] = -3.0e38f; ti5[t] = 0x7fffffff; }
#pragma unroll
  for (int m = 0; m < CH_N * KT; ++m) {
    float v = cval[b * (CH_N * KT) + m]; int id = cidx[b * (CH_N * KT) + m];
    if (v > tv5[KT - 1] || (v == tv5[KT - 1] && id < ti5[KT - 1])) {
#pragma unroll
      for (int t = 0; t < KT; ++t) {
        if (v > tv5[t] || (v == tv5[t] && id < ti5[t])) {
          float ov = tv5[t]; int oi = ti5[t];
          tv5[t] = v; ti5[t] = id; v = ov; id = oi;
        }
      }
    }
  }
  float w[KT]; int cls[KT];
#pragma unroll
  for (int t = 0; t < KT; ++t) { w[t] = expf(tv5[t]); cls[t] = y[ti5[t]]; }
  float m = -3.0e38f;
  for (int c = 0; c < Cc; ++c) {
    float f = 0.f;
#pragma unroll
    for (int t = 0; t < KT; ++t) f += (cls[t] == c) ? w[t] : 0.f;
    m = fmaxf(m, f);
  }
  float s = 0.f;
  for (int c = 0; c < Cc; ++c) {
    float f = 0.f;
#pragma unroll
    for (int t = 0; t < KT; ++t) f += (cls[t] == c) ? w[t] : 0.f;
    s += expf(f - m);
  }
  const float lse = logf(s);
  for (int c = 0; c < Cc; ++c) {
    float f = 0.f;
#pragma unroll
    for (int t = 0; t < KT; ++t) f += (cls[t] == c) ? w[t] : 0.f;
    out_final[b * Cc + c] = 0.5f * p_lc[b * Cc + c] + 0.5f * (f - m - lse);
  }
}

extern "C" void kernel_launch(void* const* d_in, const int* in_sizes, int n_in,
                              void* d_out, int out_size, void* d_ws, size_t ws_size,
                              hipStream_t stream) {
  const float* x  = (const float*)d_in[0];
  const int* erow = (const int*)d_in[1];
  const int* ecol = erow + En;
  const float* ew = (const float*)d_in[2];
  const int* y    = (const int*)d_in[3];
  const float* W1 = (const float*)d_in[5];
  const float* b1 = (const float*)d_in[6];
  const float* cw1 = (const float*)d_in[7];
  const float* cw2 = (const float*)d_in[8];
  const float* W2 = (const float*)d_in[9];
  const float* b2 = (const float*)d_in[10];
  float* out = (float*)d_out;

  float* ws = (float*)d_ws;
  size_t off = 0;
  float* plc = ws + off; off += (size_t)Bb * Cc;
  float* cval = ws + off; off += (size_t)Bb * (CH_N * KT);
  int* cidx  = (int*)(ws + off); off += (size_t)Bb * (CH_N * KT);
  int* counts = (int*)(ws + off); off += Nn;
  int* fill   = (int*)(ws + off); off += Nn;
  int* rptr   = (int*)(ws + off); off += Nn + 4;
  int2* cpair = (int2*)(ws + off); off += (size_t)2 * En;   // even offset -> 8B aligned
  unsigned short* anb = (unsigned short*)(ws + off); off += (size_t)Bb * Hd / 2;
  unsigned short* hba = (unsigned short*)(ws + off); off += (size_t)NR * Hd / 2;
  unsigned short* hbb = (unsigned short*)(ws + off); off += (size_t)NR * Hd / 2;
  unsigned short* x0b = (unsigned short*)(ws + off); off += (size_t)NR * Hd / 2;
  unsigned short* W1p = (unsigned short*)(ws + off); off += 65536 / 2;
  unsigned short* Wcp = (unsigned short*)(ws + off); off += 294912 / 2;

  k_pack_w1<<<256, 256, 0, stream>>>(W1, W1p);
  k_pack_wc<<<1152, 256, 0, stream>>>(cw1, cw2, Wcp);
  k_in<<<NR / 64, 256, 0, stream>>>(x, W1p, b1, hba, x0b);
  hipMemsetAsync(counts, 0, (size_t)2 * Nn * sizeof(int), stream);
  k_hist<<<(En + 255) / 256, 256, 0, stream>>>(erow, counts);
  k_scan2<<<(Nn + 255) / 256, 256, 0, stream>>>(counts, rptr);
  k_scatter<<<(En + 255) / 256, 256, 0, stream>>>(erow, ecol, ew, rptr, fill, cpair);
  unsigned short* hcur = hba;
  unsigned short* hnxt = hbb;
  for (int l = 0; l < Ll; ++l) {
    const float beta = logf(1.0f / (float)(l + 1) + 1.0f);
    k_fused2<<<NR / 64, 1024, 0, stream>>>(rptr, cpair, hcur, x0b,
                                           Wcp + (size_t)l * 32768, hnxt, beta);
    unsigned short* t = hcur; hcur = hnxt; hnxt = t;
  }
  k_head<<<(Bb * 64) / 256, 256, 0, stream>>>(hcur, W2, b2, anb, plc, out + (size_t)Bb * Cc);
  k_simtopk<<<((Bb + 63) / 64) * CH_N, 256, 0, stream>>>(anb, cval, cidx);
  k_final<<<(Bb + 255) / 256, 256, 0, stream>>>(cval, cidx, y, plc, out);
}

// Round 11
// 910.788 us; speedup vs baseline: 1.3756x; 1.0681x over previous
//
#include <hip/hip_runtime.h>
#include <hip/hip_bf16.h>
#include <math.h>

#define Nn  50000
#define NR  50048   // rows padded to 64
#define En  800000
#define DIN 500
#define Hd  128
#define Cc  40
#define Bb  10000
#define Ll  9
#define KT  5

typedef short bf16x8 __attribute__((ext_vector_type(8)));
typedef unsigned short u16x8 __attribute__((ext_vector_type(8)));
typedef float f32x4 __attribute__((ext_vector_type(4)));

__device__ inline float bf2f(unsigned short u) {
  union { unsigned int i; float f; } c; c.i = (unsigned int)u << 16; return c.f;
}
__device__ inline unsigned short f2bf(float f) {
  __hip_bfloat16 b = __float2bfloat16(f);
  return *(unsigned short*)&b;
}

// ---------------- weight packing into B-fragment layout ----------------
__global__ __launch_bounds__(256) void k_pack_w1(const float* __restrict__ W1,
                                                 unsigned short* __restrict__ W1p) {
  const int id = blockIdx.x * 256 + threadIdx.x;   // 16*4*128*8 = 65536
  if (id >= 65536) return;
  const int j = id & 7, col = (id >> 3) & 127, qk = id >> 10;  // qk = kk*4+quad
  const int k = (qk >> 2) * 32 + (qk & 3) * 8 + j;
  W1p[id] = f2bf((k < DIN) ? W1[(size_t)k * Hd + col] : 0.f);
}

// Wcat[l] = [W1l ; 0.5*W2l]  (K=256), same frag packing, 32768 elems/layer
__global__ __launch_bounds__(256) void k_pack_wc(const float* __restrict__ cw1,
    const float* __restrict__ cw2, unsigned short* __restrict__ Wcp) {
  const int id = blockIdx.x * 256 + threadIdx.x;   // 9*32768 = 294912
  if (id >= 294912) return;
  const int j = id & 7, col = (id >> 3) & 127, qk = (id >> 10) & 31, l = id >> 15;
  const int k = (qk >> 2) * 32 + (qk & 3) * 8 + j;  // 0..255
  float v;
  if (k < 128) v = cw1[((size_t)l * 128 + k) * 128 + col];
  else         v = 0.5f * cw2[((size_t)l * 128 + (k - 128)) * 128 + col];
  Wcp[id] = f2bf(v);
}

// ---------------- input GEMM (MFMA): hb = bf16(relu(x @ W1 + b1)) ----------------
__global__ __launch_bounds__(256) void k_in(const float* __restrict__ x,
    const unsigned short* __restrict__ W1p, const float* __restrict__ b1,
    unsigned short* __restrict__ hb, unsigned short* __restrict__ x0b) {
  const int tid = threadIdx.x;
  const int wv = tid >> 6, lane = tid & 63;
  const int lrow = lane & 15, quad = lane >> 4;
  const int row0 = blockIdx.x * 64;
  const int ar = row0 + wv * 16 + lrow;
  f32x4 acc[8];
#pragma unroll
  for (int t = 0; t < 8; ++t) acc[t] = (f32x4){0.f, 0.f, 0.f, 0.f};

  for (int kk = 0; kk < 16; ++kk) {
    const int kbase = kk * 32 + quad * 8;
    float av[8];
    if (ar < Nn) {
      if (kk < 15) {
        const float4 p0 = *(const float4*)(x + (size_t)ar * DIN + kbase);
        const float4 p1 = *(const float4*)(x + (size_t)ar * DIN + kbase + 4);
        av[0] = p0.x; av[1] = p0.y; av[2] = p0.z; av[3] = p0.w;
        av[4] = p1.x; av[5] = p1.y; av[6] = p1.z; av[7] = p1.w;
      } else {
#pragma unroll
        for (int j = 0; j < 8; ++j)
          av[j] = (kbase + j < DIN) ? x[(size_t)ar * DIN + kbase + j] : 0.f;
      }
    } else {
#pragma unroll
      for (int j = 0; j < 8; ++j) av[j] = 0.f;
    }
    bf16x8 af;
#pragma unroll
    for (int j = 0; j < 8; ++j) af[j] = (short)f2bf(av[j]);
#pragma unroll
    for (int nt = 0; nt < 8; ++nt) {
      const bf16x8 bf = *(const bf16x8*)(W1p + ((size_t)(kk * 4 + quad) * 128 + nt * 16 + lrow) * 8);
      acc[nt] = __builtin_amdgcn_mfma_f32_16x16x32_bf16(af, bf, acc[nt], 0, 0, 0);
    }
  }

  __shared__ float sacc[64 * 132];
#pragma unroll
  for (int nt = 0; nt < 8; ++nt)
#pragma unroll
    for (int i = 0; i < 4; ++i)
      sacc[(wv * 16 + quad * 4 + i) * 132 + nt * 16 + lrow] = acc[nt][i];
  __syncthreads();

  const int row = tid >> 2, cs = (tid & 3) * 32;
  const int gr = row0 + row;
  if (gr < Nn) {
#pragma unroll
    for (int g = 0; g < 4; ++g) {
      const int c0 = cs + g * 8;
      float v[8];
#pragma unroll
      for (int j = 0; j < 8; ++j)
        v[j] = fmaxf(sacc[row * 132 + c0 + j] + b1[c0 + j], 0.f);
      u16x8 ob;
#pragma unroll
      for (int j = 0; j < 8; ++j) ob[j] = f2bf(v[j]);
      *(u16x8*)(hb + (size_t)gr * Hd + c0) = ob;
      *(u16x8*)(x0b + (size_t)gr * Hd + c0) = ob;
    }
  }
}

// ---------------- CSR build ----------------
__global__ void k_hist(const int* __restrict__ rows, int* __restrict__ counts) {
  int e = blockIdx.x * 256 + threadIdx.x;
  if (e < En) atomicAdd(&counts[rows[e]], 1);
}

// Parallel scan: each block redundantly sums its prefix (L2-resident, fully
// parallel) then scans its own 256-element segment.
__global__ __launch_bounds__(256) void k_scan2(const int* __restrict__ counts,
                                               int* __restrict__ rptr) {
  __shared__ int sdata[256];
  const int b = blockIdx.x, tid = threadIdx.x;
  const int npre = b << 8;
  int s0 = 0, s1 = 0, s2 = 0, s3 = 0;
  int i = tid;
  for (; i + 768 < npre; i += 1024) {
    s0 += counts[i]; s1 += counts[i + 256]; s2 += counts[i + 512]; s3 += counts[i + 768];
  }
  for (; i < npre; i += 256) s0 += counts[i];
  sdata[tid] = s0 + s1 + s2 + s3;
  __syncthreads();
  for (int off = 128; off > 0; off >>= 1) {
    if (tid < off) sdata[tid] += sdata[tid + off];
    __syncthreads();
  }
  const int base = sdata[0];
  __syncthreads();
  const int gi = npre + tid;
  int v = (gi < Nn) ? counts[gi] : 0;
  sdata[tid] = v;
  __syncthreads();
  for (int off = 1; off < 256; off <<= 1) {
    int t = (tid >= off) ? sdata[tid - off] : 0;
    __syncthreads();
    sdata[tid] += t;
    __syncthreads();
  }
  if (gi < Nn) rptr[gi + 1] = base + sdata[tid];
  if (b == 0 && tid == 0) rptr[0] = 0;
}

// scatter (col,w) as a single int2 pair: one 8B index load per edge
__global__ void k_scatter(const int* __restrict__ rows, const int* __restrict__ cols,
                          const float* __restrict__ w, const int* __restrict__ ptr,
                          int* __restrict__ fill, int2* __restrict__ cpair) {
  int e = blockIdx.x * 256 + threadIdx.x;
  if (e >= En) return;
  int r = rows[e];
  int pos = atomicAdd(&fill[r], 1);
  int d = ptr[r] + pos;
  int2 pr; pr.x = cols[e]; pr.y = __float_as_int(w[e]);
  cpair[d] = pr;
}

// ---------------- FUSED spmm + layer, v3 (fine-grained blocks) ----------------
// v2 (1024 thr / 64 rows) worked but only netted +15us: 51KB LDS capped
// residency at 2 blocks/CU, grid 782 gave a 3.05-blocks/CU ragged tail, and
// the whole block barriered on its max-degree row. v3 halves the block:
// 512 thr / 32 rows (8 waves x 4 row-groups). LDS 25.6KB -> 4 blocks/CU
// (wave-capped, full 32-wave occupancy), grid 1564 -> 6.1/CU smooth
// interleave, per-block degree tail halves. Same per-group gather pattern.
#define PB_LD 136
#define FR 32   // rows per fused block
__global__ __launch_bounds__(512, 8) void k_fused3(const int* __restrict__ ptr,
    const int2* __restrict__ cpair, const unsigned short* __restrict__ hbr,
    const unsigned short* __restrict__ x0b, const unsigned short* __restrict__ Wcp,
    unsigned short* __restrict__ hbw, float beta) {
  __shared__ __align__(16) unsigned short pb_s[FR * PB_LD];
  __shared__ float sacc[FR * 132];
  const int tid = threadIdx.x;
  const int wv = tid >> 6;          // 0..7
  const int lane = tid & 63;
  const int grp = lane >> 4;        // row group 0..3 within wave
  const int gl = lane & 15;         // feature lane: feats gl*8..gl*8+7
  const int row0 = blockIdx.x * FR;
  const int lr = wv * 4 + grp;      // local row 0..31
  const int row = row0 + lr;

  // ---- phase A: gather (one row per 16-lane group, all rows in parallel)
  float acc[8];
#pragma unroll
  for (int j = 0; j < 8; ++j) acc[j] = 0.f;

  auto acc8 = [&](uint4 v, float w) {
    union { unsigned int i; float f; } t;
    t.i = v.x << 16;         acc[0] += w * t.f;
    t.i = v.x & 0xFFFF0000u; acc[1] += w * t.f;
    t.i = v.y << 16;         acc[2] += w * t.f;
    t.i = v.y & 0xFFFF0000u; acc[3] += w * t.f;
    t.i = v.z << 16;         acc[4] += w * t.f;
    t.i = v.z & 0xFFFF0000u; acc[5] += w * t.f;
    t.i = v.w << 16;         acc[6] += w * t.f;
    t.i = v.w & 0xFFFF0000u; acc[7] += w * t.f;
  };

  if (row < Nn) {
    const int s = ptr[row], e_end = ptr[row + 1];
    int e = s;
    for (; e + 3 < e_end; e += 4) {
      const int2 p0 = cpair[e];
      const int2 p1 = cpair[e + 1];
      const int2 p2 = cpair[e + 2];
      const int2 p3 = cpair[e + 3];
      const uint4 v0 = *(const uint4*)(hbr + (size_t)p0.x * Hd + gl * 8);
      const uint4 v1 = *(const uint4*)(hbr + (size_t)p1.x * Hd + gl * 8);
      const uint4 v2 = *(const uint4*)(hbr + (size_t)p2.x * Hd + gl * 8);
      const uint4 v3 = *(const uint4*)(hbr + (size_t)p3.x * Hd + gl * 8);
      acc8(v0, __int_as_float(p0.y)); acc8(v1, __int_as_float(p1.y));
      acc8(v2, __int_as_float(p2.y)); acc8(v3, __int_as_float(p3.y));
    }
    for (; e < e_end; ++e) {
      const int2 p0 = cpair[e];
      const uint4 v = *(const uint4*)(hbr + (size_t)p0.x * Hd + gl * 8);
      acc8(v, __int_as_float(p0.y));
    }
  }
  {
    uint4 o;
    o.x = (unsigned int)f2bf(0.5f * acc[0]) | ((unsigned int)f2bf(0.5f * acc[1]) << 16);
    o.y = (unsigned int)f2bf(0.5f * acc[2]) | ((unsigned int)f2bf(0.5f * acc[3]) << 16);
    o.z = (unsigned int)f2bf(0.5f * acc[4]) | ((unsigned int)f2bf(0.5f * acc[5]) << 16);
    o.w = (unsigned int)f2bf(0.5f * acc[6]) | ((unsigned int)f2bf(0.5f * acc[7]) << 16);
    *(uint4*)&pb_s[lr * PB_LD + gl * 8] = o;
  }
  __syncthreads();

  // ---- phase B: 32x128 layer GEMM; 2 row-frags x 8 col-frags = 16 tiles,
  // 8 waves x 2 tiles. wave wv: rf = wv>>2 (0..1), cf = (wv&3)*2 + {0,1}.
  const int lrow = lane & 15, quad = lane >> 4;
  const int rf = wv >> 2;
  const int cf0 = (wv & 3) * 2;
  const int arl = rf * 16 + lrow;
  const int ar = row0 + arl;
  f32x4 gacc[2];
  gacc[0] = (f32x4){0.f, 0.f, 0.f, 0.f};
  gacc[1] = (f32x4){0.f, 0.f, 0.f, 0.f};
#pragma unroll
  for (int kk = 0; kk < 8; ++kk) {
    const int ko = (kk & 3) * 32 + quad * 8;
    bf16x8 af;
    if (kk < 4) af = *(const bf16x8*)&pb_s[arl * PB_LD + ko];
    else        af = *(const bf16x8*)(x0b + (size_t)ar * Hd + ko);
#pragma unroll
    for (int t = 0; t < 2; ++t) {
      const bf16x8 bf = *(const bf16x8*)(Wcp + ((size_t)(kk * 4 + quad) * 128 + (cf0 + t) * 16 + lrow) * 8);
      gacc[t] = __builtin_amdgcn_mfma_f32_16x16x32_bf16(af, bf, gacc[t], 0, 0, 0);
    }
  }
#pragma unroll
  for (int t = 0; t < 2; ++t)
#pragma unroll
    for (int i = 0; i < 4; ++i)
      sacc[(rf * 16 + quad * 4 + i) * 132 + (cf0 + t) * 16 + lrow] = gacc[t][i];
  __syncthreads();

  // ---- epilogue: 512 threads, 8 outputs each (32 rows x 128 cols)
  const int erow = tid >> 4, cs = (tid & 15) * 8;
  const int gr = row0 + erow;
  if (gr < Nn) {
    const float om = 1.f - beta;
    const u16x8 pv = *(const u16x8*)&pb_s[erow * PB_LD + cs];
    const u16x8 xv = *(const u16x8*)(x0b + (size_t)gr * Hd + cs);
    const u16x8 hv = *(const u16x8*)(hbr + (size_t)gr * Hd + cs);
    float nv[8];
#pragma unroll
    for (int j = 0; j < 8; ++j) {
      const float gemm = sacc[erow * 132 + cs + j];
      const float pj = bf2f(pv[j]);
      const float xj = bf2f(xv[j]);
      const float outv = om * (pj + 0.5f * xj) + beta * gemm;
      nv[j] = fmaxf(bf2f(hv[j]) + outv, 0.f);
    }
    u16x8 ob;
#pragma unroll
    for (int j = 0; j < 8; ++j) ob[j] = f2bf(nv[j]);
    *(u16x8*)(hbw + (size_t)gr * Hd + cs) = ob;
  }
}

// ---------------- head (reads bf16 hb) ----------------
__global__ __launch_bounds__(256) void k_head(const unsigned short* __restrict__ hb,
    const float* __restrict__ W2, const float* __restrict__ b2,
    unsigned short* __restrict__ anb, float* __restrict__ p_lc,
    float* __restrict__ out_emb) {
  const int wid = (blockIdx.x * 256 + threadIdx.x) >> 6;
  const int lane = threadIdx.x & 63;
  if (wid >= Bb) return;
  const unsigned short* hr = hb + (size_t)wid * Hd;
  const float v0 = bf2f(hr[lane]), v1 = bf2f(hr[lane + 64]);
  out_emb[wid * Hd + lane] = v0;
  out_emb[wid * Hd + lane + 64] = v1;
  float ss = v0 * v0 + v1 * v1;
#pragma unroll
  for (int off = 32; off > 0; off >>= 1) ss += __shfl_xor(ss, off);
  const float inv = 1.f / fmaxf(sqrtf(ss), 1e-8f);
  anb[wid * Hd + lane] = f2bf(v0 * inv);
  anb[wid * Hd + lane + 64] = f2bf(v1 * inv);
  float l = 0.f;
  if (lane < Cc) {
    for (int k = 0; k < Hd; ++k) l += bf2f(hr[k]) * W2[k * Cc + lane];
    l += b2[lane];
  }
  float lm = (lane < Cc) ? l : -3.0e38f;
#pragma unroll
  for (int off = 32; off > 0; off >>= 1) lm = fmaxf(lm, __shfl_xor(lm, off));
  float ex = (lane < Cc) ? expf(l - lm) : 0.f;
#pragma unroll
  for (int off = 32; off > 0; off >>= 1) ex += __shfl_xor(ex, off);
  const float lse = logf(ex);
  if (lane < Cc) p_lc[wid * Cc + lane] = l - lm - lse;
}

// ---------------- fused sim = an@an^T (bf16 MFMA) with running top-5 ----------
// FROZEN at the r0 structure (144.5 us re-confirmed r10 — best of 6 variants;
// minthr gate, CH_N 8/16, u64 keys, ballot gate, butterfly all regressed).
#define CH_N  4
#define CH_SZ 2500
#define SB_LD 136
__global__ __launch_bounds__(256) void k_simtopk(const unsigned short* __restrict__ anb,
    float* __restrict__ cval, int* __restrict__ cidx) {
  __shared__ __align__(16) char smem[40960];
  unsigned short* sb = (unsigned short*)smem;
  const int rt = blockIdx.x / CH_N;
  const int chunk = blockIdx.x % CH_N;
  const int row0 = rt * 64;
  const int cbeg = chunk * CH_SZ;
  const int cend = cbeg + CH_SZ;
  const int tid = threadIdx.x;
  const int wv = tid >> 6;
  const int lane = tid & 63;
  const int lrow = lane & 15;
  const int quad = lane >> 4;

  union Frag { uint4 u4; bf16x8 v; };
  bf16x8 afr[4];
  const int ar = row0 + wv * 16 + lrow;
#pragma unroll
  for (int kq = 0; kq < 4; ++kq) {
    Frag f;
    f.u4 = make_uint4(0u, 0u, 0u, 0u);
    if (ar < Bb) f.u4 = *(const uint4*)(anb + (size_t)ar * Hd + kq * 32 + quad * 8);
    afr[kq] = f.v;
  }

  float bv[4][KT];
  int bi[4][KT];
#pragma unroll
  for (int r = 0; r < 4; ++r)
#pragma unroll
    for (int t = 0; t < KT; ++t) { bv[r][t] = -3.0e38f; bi[r][t] = 0x7fffffff; }

  const int ntile = (CH_SZ + 63) / 64;
  for (int t = 0; t < ntile; ++t) {
    const int c0 = cbeg + t * 64;
    __syncthreads();
    for (int i = tid; i < 1024; i += 256) {
      const int r = i >> 4, ch = i & 15;
      const int gc = c0 + r;
      uint4 v = make_uint4(0u, 0u, 0u, 0u);
      if (gc < cend) v = *(const uint4*)(anb + (size_t)gc * Hd + ch * 8);
      *(uint4*)&sb[r * SB_LD + ch * 8] = v;
    }
    __syncthreads();
#pragma unroll
    for (int sub = 0; sub < 4; ++sub) {
      f32x4 acc = {0.f, 0.f, 0.f, 0.f};
      const int scol = sub * 16 + lrow;
#pragma unroll
      for (int kq = 0; kq < 4; ++kq) {
        bf16x8 bfr = *(const bf16x8*)&sb[scol * SB_LD + kq * 32 + quad * 8];
        acc = __builtin_amdgcn_mfma_f32_16x16x32_bf16(afr[kq], bfr, acc, 0, 0, 0);
      }
      const int gc = c0 + scol;
      const bool ok = gc < cend;
#pragma unroll
      for (int i = 0; i < 4; ++i) {
        const float v = ok ? acc[i] : -3.0e38f;
        if (v > bv[i][KT - 1]) {
          float tv = v; int ti = gc;
#pragma unroll
          for (int s = 0; s < KT; ++s) {
            if (tv > bv[i][s]) {
              float ov = bv[i][s]; int oi = bi[i][s];
              bv[i][s] = tv; bi[i][s] = ti; tv = ov; ti = oi;
            }
          }
        }
      }
    }
  }

  __syncthreads();
  float* mv = (float*)smem;
  int* mi = (int*)(smem + 20480);
#pragma unroll
  for (int i = 0; i < 4; ++i) {
    const int row = wv * 16 + quad * 4 + i;
#pragma unroll
    for (int t = 0; t < KT; ++t) {
      mv[row * 80 + lrow * KT + t] = bv[i][t];
      mi[row * 80 + lrow * KT + t] = bi[i][t];
    }
  }
  __syncthreads();
  if (tid < 64) {
    const int gr = row0 + tid;
    if (gr < Bb) {
      float tv5[KT]; int ti5[KT];
#pragma unroll
      for (int t = 0; t < KT; ++t) { tv5[t] = -3.0e38f; ti5[t] = 0x7fffffff; }
      for (int m = 0; m < 80; ++m) {
        float v = mv[tid * 80 + m]; int id = mi[tid * 80 + m];
        if (v > tv5[KT - 1] || (v == tv5[KT - 1] && id < ti5[KT - 1])) {
#pragma unroll
          for (int s = 0; s < KT; ++s) {
            if (v > tv5[s] || (v == tv5[s] && id < ti5[s])) {
              float ov = tv5[s]; int oi = ti5[s];
              tv5[s] = v; ti5[s] = id; v = ov; id = oi;
            }
          }
        }
      }
#pragma unroll
      for (int t = 0; t < KT; ++t) {
        cval[gr * (CH_N * KT) + chunk * KT + t] = tv5[t];
        cidx[gr * (CH_N * KT) + chunk * KT + t] = ti5[t];
      }
    }
  }
}

// ---------------- final ----------------
__global__ __launch_bounds__(256) void k_final(const float* __restrict__ cval,
    const int* __restrict__ cidx, const int* __restrict__ y,
    const float* __restrict__ p_lc, float* __restrict__ out_final) {
  const int b = blockIdx.x * 256 + threadIdx.x;
  if (b >= Bb) return;
  float tv5[KT]; int ti5[KT];
#pragma unroll
  for (int t = 0; t < KT; ++t) { tv5[t] = -3.0e38f; ti5[t] = 0x7fffffff; }
#pragma unroll
  for (int m = 0; m < CH_N * KT; ++m) {
    float v = cval[b * (CH_N * KT) + m]; int id = cidx[b * (CH_N * KT) + m];
    if (v > tv5[KT - 1] || (v == tv5[KT - 1] && id < ti5[KT - 1])) {
#pragma unroll
      for (int t = 0; t < KT; ++t) {
        if (v > tv5[t] || (v == tv5[t] && id < ti5[t])) {
          float ov = tv5[t]; int oi = ti5[t];
          tv5[t] = v; ti5[t] = id; v = ov; id = oi;
        }
      }
    }
  }
  float w[KT]; int cls[KT];
#pragma unroll
  for (int t = 0; t < KT; ++t) { w[t] = expf(tv5[t]); cls[t] = y[ti5[t]]; }
  float m = -3.0e38f;
  for (int c = 0; c < Cc; ++c) {
    float f = 0.f;
#pragma unroll
    for (int t = 0; t < KT; ++t) f += (cls[t] == c) ? w[t] : 0.f;
    m = fmaxf(m, f);
  }
  float s = 0.f;
  for (int c = 0; c < Cc; ++c) {
    float f = 0.f;
#pragma unroll
    for (int t = 0; t < KT; ++t) f += (cls[t] == c) ? w[t] : 0.f;
    s += expf(f - m);
  }
  const float lse = logf(s);
  for (int c = 0; c < Cc; ++c) {
    float f = 0.f;
#pragma unroll
    for (int t = 0; t < KT; ++t) f += (cls[t] == c) ? w[t] : 0.f;
    out_final[b * Cc + c] = 0.5f * p_lc[b * Cc + c] + 0.5f * (f - m - lse);
  }
}

extern "C" void kernel_launch(void* const* d_in, const int* in_sizes, int n_in,
                              void* d_out, int out_size, void* d_ws, size_t ws_size,
                              hipStream_t stream) {
  const float* x  = (const float*)d_in[0];
  const int* erow = (const int*)d_in[1];
  const int* ecol = erow + En;
  const float* ew = (const float*)d_in[2];
  const int* y    = (const int*)d_in[3];
  const float* W1 = (const float*)d_in[5];
  const float* b1 = (const float*)d_in[6];
  const float* cw1 = (const float*)d_in[7];
  const float* cw2 = (const float*)d_in[8];
  const float* W2 = (const float*)d_in[9];
  const float* b2 = (const float*)d_in[10];
  float* out = (float*)d_out;

  float* ws = (float*)d_ws;
  size_t off = 0;
  float* plc = ws + off; off += (size_t)Bb * Cc;
  float* cval = ws + off; off += (size_t)Bb * (CH_N * KT);
  int* cidx  = (int*)(ws + off); off += (size_t)Bb * (CH_N * KT);
  int* counts = (int*)(ws + off); off += Nn;
  int* fill   = (int*)(ws + off); off += Nn;
  int* rptr   = (int*)(ws + off); off += Nn + 4;
  int2* cpair = (int2*)(ws + off); off += (size_t)2 * En;   // even offset -> 8B aligned
  unsigned short* anb = (unsigned short*)(ws + off); off += (size_t)Bb * Hd / 2;
  unsigned short* hba = (unsigned short*)(ws + off); off += (size_t)NR * Hd / 2;
  unsigned short* hbb = (unsigned short*)(ws + off); off += (size_t)NR * Hd / 2;
  unsigned short* x0b = (unsigned short*)(ws + off); off += (size_t)NR * Hd / 2;
  unsigned short* W1p = (unsigned short*)(ws + off); off += 65536 / 2;
  unsigned short* Wcp = (unsigned short*)(ws + off); off += 294912 / 2;

  k_pack_w1<<<256, 256, 0, stream>>>(W1, W1p);
  k_pack_wc<<<1152, 256, 0, stream>>>(cw1, cw2, Wcp);
  k_in<<<NR / 64, 256, 0, stream>>>(x, W1p, b1, hba, x0b);
  hipMemsetAsync(counts, 0, (size_t)2 * Nn * sizeof(int), stream);
  k_hist<<<(En + 255) / 256, 256, 0, stream>>>(erow, counts);
  k_scan2<<<(Nn + 255) / 256, 256, 0, stream>>>(counts, rptr);
  k_scatter<<<(En + 255) / 256, 256, 0, stream>>>(erow, ecol, ew, rptr, fill, cpair);
  unsigned short* hcur = hba;
  unsigned short* hnxt = hbb;
  for (int l = 0; l < Ll; ++l) {
    const float beta = logf(1.0f / (float)(l + 1) + 1.0f);
    k_fused3<<<NR / FR, 512, 0, stream>>>(rptr, cpair, hcur, x0b,
                                          Wcp + (size_t)l * 32768, hnxt, beta);
    unsigned short* t = hcur; hcur = hnxt; hnxt = t;
  }
  k_head<<<(Bb * 64) / 256, 256, 0, stream>>>(hcur, W2, b2, anb, plc, out + (size_t)Bb * Cc);
  k_simtopk<<<((Bb + 63) / 64) * CH_N, 256, 0, stream>>>(anb, cval, cidx);
  k_final<<<(Bb + 255) / 256, 256, 0, stream>>>(cval, cidx, y, plc, out);
}

// Round 12
// 897.389 us; speedup vs baseline: 1.3961x; 1.0149x over previous
//
#include <hip/hip_runtime.h>
#include <hip/hip_bf16.h>
#include <math.h>

#define Nn  50000
#define NR  50048   // rows padded to 64
#define En  800000
#define DIN 500
#define Hd  128
#define Cc  40
#define Bb  10000
#define Ll  9
#define KT  5

typedef short bf16x8 __attribute__((ext_vector_type(8)));
typedef unsigned short u16x8 __attribute__((ext_vector_type(8)));
typedef float f32x4 __attribute__((ext_vector_type(4)));

__device__ inline float bf2f(unsigned short u) {
  union { unsigned int i; float f; } c; c.i = (unsigned int)u << 16; return c.f;
}
__device__ inline unsigned short f2bf(float f) {
  __hip_bfloat16 b = __float2bfloat16(f);
  return *(unsigned short*)&b;
}

// ---------------- weight packing into B-fragment layout ----------------
__global__ __launch_bounds__(256) void k_pack_w1(const float* __restrict__ W1,
                                                 unsigned short* __restrict__ W1p) {
  const int id = blockIdx.x * 256 + threadIdx.x;   // 16*4*128*8 = 65536
  if (id >= 65536) return;
  const int j = id & 7, col = (id >> 3) & 127, qk = id >> 10;  // qk = kk*4+quad
  const int k = (qk >> 2) * 32 + (qk & 3) * 8 + j;
  W1p[id] = f2bf((k < DIN) ? W1[(size_t)k * Hd + col] : 0.f);
}

// Wcat[l] = [W1l ; 0.5*W2l]  (K=256), same frag packing, 32768 elems/layer
__global__ __launch_bounds__(256) void k_pack_wc(const float* __restrict__ cw1,
    const float* __restrict__ cw2, unsigned short* __restrict__ Wcp) {
  const int id = blockIdx.x * 256 + threadIdx.x;   // 9*32768 = 294912
  if (id >= 294912) return;
  const int j = id & 7, col = (id >> 3) & 127, qk = (id >> 10) & 31, l = id >> 15;
  const int k = (qk >> 2) * 32 + (qk & 3) * 8 + j;  // 0..255
  float v;
  if (k < 128) v = cw1[((size_t)l * 128 + k) * 128 + col];
  else         v = 0.5f * cw2[((size_t)l * 128 + (k - 128)) * 128 + col];
  Wcp[id] = f2bf(v);
}

// ---------------- input GEMM (MFMA): hb = bf16(relu(x @ W1 + b1)) ----------------
__global__ __launch_bounds__(256) void k_in(const float* __restrict__ x,
    const unsigned short* __restrict__ W1p, const float* __restrict__ b1,
    unsigned short* __restrict__ hb, unsigned short* __restrict__ x0b) {
  const int tid = threadIdx.x;
  const int wv = tid >> 6, lane = tid & 63;
  const int lrow = lane & 15, quad = lane >> 4;
  const int row0 = blockIdx.x * 64;
  const int ar = row0 + wv * 16 + lrow;
  f32x4 acc[8];
#pragma unroll
  for (int t = 0; t < 8; ++t) acc[t] = (f32x4){0.f, 0.f, 0.f, 0.f};

  for (int kk = 0; kk < 16; ++kk) {
    const int kbase = kk * 32 + quad * 8;
    float av[8];
    if (ar < Nn) {
      if (kk < 15) {
        const float4 p0 = *(const float4*)(x + (size_t)ar * DIN + kbase);
        const float4 p1 = *(const float4*)(x + (size_t)ar * DIN + kbase + 4);
        av[0] = p0.x; av[1] = p0.y; av[2] = p0.z; av[3] = p0.w;
        av[4] = p1.x; av[5] = p1.y; av[6] = p1.z; av[7] = p1.w;
      } else {
#pragma unroll
        for (int j = 0; j < 8; ++j)
          av[j] = (kbase + j < DIN) ? x[(size_t)ar * DIN + kbase + j] : 0.f;
      }
    } else {
#pragma unroll
      for (int j = 0; j < 8; ++j) av[j] = 0.f;
    }
    bf16x8 af;
#pragma unroll
    for (int j = 0; j < 8; ++j) af[j] = (short)f2bf(av[j]);
#pragma unroll
    for (int nt = 0; nt < 8; ++nt) {
      const bf16x8 bf = *(const bf16x8*)(W1p + ((size_t)(kk * 4 + quad) * 128 + nt * 16 + lrow) * 8);
      acc[nt] = __builtin_amdgcn_mfma_f32_16x16x32_bf16(af, bf, acc[nt], 0, 0, 0);
    }
  }

  __shared__ float sacc[64 * 132];
#pragma unroll
  for (int nt = 0; nt < 8; ++nt)
#pragma unroll
    for (int i = 0; i < 4; ++i)
      sacc[(wv * 16 + quad * 4 + i) * 132 + nt * 16 + lrow] = acc[nt][i];
  __syncthreads();

  const int row = tid >> 2, cs = (tid & 3) * 32;
  const int gr = row0 + row;
  if (gr < Nn) {
#pragma unroll
    for (int g = 0; g < 4; ++g) {
      const int c0 = cs + g * 8;
      float v[8];
#pragma unroll
      for (int j = 0; j < 8; ++j)
        v[j] = fmaxf(sacc[row * 132 + c0 + j] + b1[c0 + j], 0.f);
      u16x8 ob;
#pragma unroll
      for (int j = 0; j < 8; ++j) ob[j] = f2bf(v[j]);
      *(u16x8*)(hb + (size_t)gr * Hd + c0) = ob;
      *(u16x8*)(x0b + (size_t)gr * Hd + c0) = ob;
    }
  }
}

// ---------------- CSR build ----------------
__global__ void k_hist(const int* __restrict__ rows, int* __restrict__ counts) {
  int e = blockIdx.x * 256 + threadIdx.x;
  if (e < En) atomicAdd(&counts[rows[e]], 1);
}

// Parallel scan: each block redundantly sums its prefix (L2-resident, fully
// parallel) then scans its own 256-element segment.
__global__ __launch_bounds__(256) void k_scan2(const int* __restrict__ counts,
                                               int* __restrict__ rptr) {
  __shared__ int sdata[256];
  const int b = blockIdx.x, tid = threadIdx.x;
  const int npre = b << 8;
  int s0 = 0, s1 = 0, s2 = 0, s3 = 0;
  int i = tid;
  for (; i + 768 < npre; i += 1024) {
    s0 += counts[i]; s1 += counts[i + 256]; s2 += counts[i + 512]; s3 += counts[i + 768];
  }
  for (; i < npre; i += 256) s0 += counts[i];
  sdata[tid] = s0 + s1 + s2 + s3;
  __syncthreads();
  for (int off = 128; off > 0; off >>= 1) {
    if (tid < off) sdata[tid] += sdata[tid + off];
    __syncthreads();
  }
  const int base = sdata[0];
  __syncthreads();
  const int gi = npre + tid;
  int v = (gi < Nn) ? counts[gi] : 0;
  sdata[tid] = v;
  __syncthreads();
  for (int off = 1; off < 256; off <<= 1) {
    int t = (tid >= off) ? sdata[tid - off] : 0;
    __syncthreads();
    sdata[tid] += t;
    __syncthreads();
  }
  if (gi < Nn) rptr[gi + 1] = base + sdata[tid];
  if (b == 0 && tid == 0) rptr[0] = 0;
}

// scatter (col,w) as a single int2 pair: one 8B index load per edge
__global__ void k_scatter(const int* __restrict__ rows, const int* __restrict__ cols,
                          const float* __restrict__ w, const int* __restrict__ ptr,
                          int* __restrict__ fill, int2* __restrict__ cpair) {
  int e = blockIdx.x * 256 + threadIdx.x;
  if (e >= En) return;
  int r = rows[e];
  int pos = atomicAdd(&fill[r], 1);
  int d = ptr[r] + pos;
  int2 pr; pr.x = cols[e]; pr.y = __float_as_int(w[e]);
  cpair[d] = pr;
}

// ---------------- FUSED spmm + layer, v4 (finest-grained blocks) ----------------
// Confirmed gradient: v2 (1024thr/64rows, 2 blk/CU) -> v3 (512/32, 4 blk/CU)
// gained 62us at IDENTICAL wave occupancy — the win is smaller barrier scope,
// halved per-block degree-tail, smoother interleave. v4 continues: 256 thr /
// 16 rows (4 waves x 4 row-groups). LDS 12.8KB -> 8 blocks/CU (wave-capped),
// grid 3128 -> 12.2 blocks/CU schedulable, degree-tail max16~24 vs max32~27.
#define PB_LD 136
#define FR 16   // rows per fused block
__global__ __launch_bounds__(256, 8) void k_fused4(const int* __restrict__ ptr,
    const int2* __restrict__ cpair, const unsigned short* __restrict__ hbr,
    const unsigned short* __restrict__ x0b, const unsigned short* __restrict__ Wcp,
    unsigned short* __restrict__ hbw, float beta) {
  __shared__ __align__(16) unsigned short pb_s[FR * PB_LD];
  __shared__ float sacc[FR * 132];
  const int tid = threadIdx.x;
  const int wv = tid >> 6;          // 0..3
  const int lane = tid & 63;
  const int grp = lane >> 4;        // row group 0..3 within wave
  const int gl = lane & 15;         // feature lane: feats gl*8..gl*8+7
  const int row0 = blockIdx.x * FR;
  const int lr = wv * 4 + grp;      // local row 0..15
  const int row = row0 + lr;

  // ---- phase A: gather (one row per 16-lane group, all rows in parallel)
  float acc[8];
#pragma unroll
  for (int j = 0; j < 8; ++j) acc[j] = 0.f;

  auto acc8 = [&](uint4 v, float w) {
    union { unsigned int i; float f; } t;
    t.i = v.x << 16;         acc[0] += w * t.f;
    t.i = v.x & 0xFFFF0000u; acc[1] += w * t.f;
    t.i = v.y << 16;         acc[2] += w * t.f;
    t.i = v.y & 0xFFFF0000u; acc[3] += w * t.f;
    t.i = v.z << 16;         acc[4] += w * t.f;
    t.i = v.z & 0xFFFF0000u; acc[5] += w * t.f;
    t.i = v.w << 16;         acc[6] += w * t.f;
    t.i = v.w & 0xFFFF0000u; acc[7] += w * t.f;
  };

  if (row < Nn) {
    const int s = ptr[row], e_end = ptr[row + 1];
    int e = s;
    for (; e + 3 < e_end; e += 4) {
      const int2 p0 = cpair[e];
      const int2 p1 = cpair[e + 1];
      const int2 p2 = cpair[e + 2];
      const int2 p3 = cpair[e + 3];
      const uint4 v0 = *(const uint4*)(hbr + (size_t)p0.x * Hd + gl * 8);
      const uint4 v1 = *(const uint4*)(hbr + (size_t)p1.x * Hd + gl * 8);
      const uint4 v2 = *(const uint4*)(hbr + (size_t)p2.x * Hd + gl * 8);
      const uint4 v3 = *(const uint4*)(hbr + (size_t)p3.x * Hd + gl * 8);
      acc8(v0, __int_as_float(p0.y)); acc8(v1, __int_as_float(p1.y));
      acc8(v2, __int_as_float(p2.y)); acc8(v3, __int_as_float(p3.y));
    }
    for (; e < e_end; ++e) {
      const int2 p0 = cpair[e];
      const uint4 v = *(const uint4*)(hbr + (size_t)p0.x * Hd + gl * 8);
      acc8(v, __int_as_float(p0.y));
    }
  }
  {
    uint4 o;
    o.x = (unsigned int)f2bf(0.5f * acc[0]) | ((unsigned int)f2bf(0.5f * acc[1]) << 16);
    o.y = (unsigned int)f2bf(0.5f * acc[2]) | ((unsigned int)f2bf(0.5f * acc[3]) << 16);
    o.z = (unsigned int)f2bf(0.5f * acc[4]) | ((unsigned int)f2bf(0.5f * acc[5]) << 16);
    o.w = (unsigned int)f2bf(0.5f * acc[6]) | ((unsigned int)f2bf(0.5f * acc[7]) << 16);
    *(uint4*)&pb_s[lr * PB_LD + gl * 8] = o;
  }
  __syncthreads();

  // ---- phase B: 16x128 layer GEMM; 1 row-frag x 8 col-frags = 8 tiles,
  // 4 waves x 2 tiles. wave wv: cf = wv*2 + {0,1}.
  const int lrow = lane & 15, quad = lane >> 4;
  const int cf0 = wv * 2;
  const int arl = lrow;
  const int ar = row0 + arl;
  f32x4 gacc[2];
  gacc[0] = (f32x4){0.f, 0.f, 0.f, 0.f};
  gacc[1] = (f32x4){0.f, 0.f, 0.f, 0.f};
#pragma unroll
  for (int kk = 0; kk < 8; ++kk) {
    const int ko = (kk & 3) * 32 + quad * 8;
    bf16x8 af;
    if (kk < 4) af = *(const bf16x8*)&pb_s[arl * PB_LD + ko];
    else        af = *(const bf16x8*)(x0b + (size_t)ar * Hd + ko);
#pragma unroll
    for (int t = 0; t < 2; ++t) {
      const bf16x8 bf = *(const bf16x8*)(Wcp + ((size_t)(kk * 4 + quad) * 128 + (cf0 + t) * 16 + lrow) * 8);
      gacc[t] = __builtin_amdgcn_mfma_f32_16x16x32_bf16(af, bf, gacc[t], 0, 0, 0);
    }
  }
#pragma unroll
  for (int t = 0; t < 2; ++t)
#pragma unroll
    for (int i = 0; i < 4; ++i)
      sacc[(quad * 4 + i) * 132 + (cf0 + t) * 16 + lrow] = gacc[t][i];
  __syncthreads();

  // ---- epilogue: 256 threads, 8 outputs each (16 rows x 128 cols)
  const int erow = tid >> 4, cs = (tid & 15) * 8;
  const int gr = row0 + erow;
  if (gr < Nn) {
    const float om = 1.f - beta;
    const u16x8 pv = *(const u16x8*)&pb_s[erow * PB_LD + cs];
    const u16x8 xv = *(const u16x8*)(x0b + (size_t)gr * Hd + cs);
    const u16x8 hv = *(const u16x8*)(hbr + (size_t)gr * Hd + cs);
    float nv[8];
#pragma unroll
    for (int j = 0; j < 8; ++j) {
      const float gemm = sacc[erow * 132 + cs + j];
      const float pj = bf2f(pv[j]);
      const float xj = bf2f(xv[j]);
      const float outv = om * (pj + 0.5f * xj) + beta * gemm;
      nv[j] = fmaxf(bf2f(hv[j]) + outv, 0.f);
    }
    u16x8 ob;
#pragma unroll
    for (int j = 0; j < 8; ++j) ob[j] = f2bf(nv[j]);
    *(u16x8*)(hbw + (size_t)gr * Hd + cs) = ob;
  }
}

// ---------------- head (reads bf16 hb) ----------------
__global__ __launch_bounds__(256) void k_head(const unsigned short* __restrict__ hb,
    const float* __restrict__ W2, const float* __restrict__ b2,
    unsigned short* __restrict__ anb, float* __restrict__ p_lc,
    float* __restrict__ out_emb) {
  const int wid = (blockIdx.x * 256 + threadIdx.x) >> 6;
  const int lane = threadIdx.x & 63;
  if (wid >= Bb) return;
  const unsigned short* hr = hb + (size_t)wid * Hd;
  const float v0 = bf2f(hr[lane]), v1 = bf2f(hr[lane + 64]);
  out_emb[wid * Hd + lane] = v0;
  out_emb[wid * Hd + lane + 64] = v1;
  float ss = v0 * v0 + v1 * v1;
#pragma unroll
  for (int off = 32; off > 0; off >>= 1) ss += __shfl_xor(ss, off);
  const float inv = 1.f / fmaxf(sqrtf(ss), 1e-8f);
  anb[wid * Hd + lane] = f2bf(v0 * inv);
  anb[wid * Hd + lane + 64] = f2bf(v1 * inv);
  float l = 0.f;
  if (lane < Cc) {
    for (int k = 0; k < Hd; ++k) l += bf2f(hr[k]) * W2[k * Cc + lane];
    l += b2[lane];
  }
  float lm = (lane < Cc) ? l : -3.0e38f;
#pragma unroll
  for (int off = 32; off > 0; off >>= 1) lm = fmaxf(lm, __shfl_xor(lm, off));
  float ex = (lane < Cc) ? expf(l - lm) : 0.f;
#pragma unroll
  for (int off = 32; off > 0; off >>= 1) ex += __shfl_xor(ex, off);
  const float lse = logf(ex);
  if (lane < Cc) p_lc[wid * Cc + lane] = l - lm - lse;
}

// ---------------- fused sim = an@an^T (bf16 MFMA) with running top-5 ----------
// FROZEN at the r0 structure (144.5-145 us re-confirmed r10/r11 — best of 6
// variants; minthr gate, CH_N 8/16, u64 keys, ballot gate, butterfly all
// regressed). Do not touch.
#define CH_N  4
#define CH_SZ 2500
#define SB_LD 136
__global__ __launch_bounds__(256) void k_simtopk(const unsigned short* __restrict__ anb,
    float* __restrict__ cval, int* __restrict__ cidx) {
  __shared__ __align__(16) char smem[40960];
  unsigned short* sb = (unsigned short*)smem;
  const int rt = blockIdx.x / CH_N;
  const int chunk = blockIdx.x % CH_N;
  const int row0 = rt * 64;
  const int cbeg = chunk * CH_SZ;
  const int cend = cbeg + CH_SZ;
  const int tid = threadIdx.x;
  const int wv = tid >> 6;
  const int lane = tid & 63;
  const int lrow = lane & 15;
  const int quad = lane >> 4;

  union Frag { uint4 u4; bf16x8 v; };
  bf16x8 afr[4];
  const int ar = row0 + wv * 16 + lrow;
#pragma unroll
  for (int kq = 0; kq < 4; ++kq) {
    Frag f;
    f.u4 = make_uint4(0u, 0u, 0u, 0u);
    if (ar < Bb) f.u4 = *(const uint4*)(anb + (size_t)ar * Hd + kq * 32 + quad * 8);
    afr[kq] = f.v;
  }

  float bv[4][KT];
  int bi[4][KT];
#pragma unroll
  for (int r = 0; r < 4; ++r)
#pragma unroll
    for (int t = 0; t < KT; ++t) { bv[r][t] = -3.0e38f; bi[r][t] = 0x7fffffff; }

  const int ntile = (CH_SZ + 63) / 64;
  for (int t = 0; t < ntile; ++t) {
    const int c0 = cbeg + t * 64;
    __syncthreads();
    for (int i = tid; i < 1024; i += 256) {
      const int r = i >> 4, ch = i & 15;
      const int gc = c0 + r;
      uint4 v = make_uint4(0u, 0u, 0u, 0u);
      if (gc < cend) v = *(const uint4*)(anb + (size_t)gc * Hd + ch * 8);
      *(uint4*)&sb[r * SB_LD + ch * 8] = v;
    }
    __syncthreads();
#pragma unroll
    for (int sub = 0; sub < 4; ++sub) {
      f32x4 acc = {0.f, 0.f, 0.f, 0.f};
      const int scol = sub * 16 + lrow;
#pragma unroll
      for (int kq = 0; kq < 4; ++kq) {
        bf16x8 bfr = *(const bf16x8*)&sb[scol * SB_LD + kq * 32 + quad * 8];
        acc = __builtin_amdgcn_mfma_f32_16x16x32_bf16(afr[kq], bfr, acc, 0, 0, 0);
      }
      const int gc = c0 + scol;
      const bool ok = gc < cend;
#pragma unroll
      for (int i = 0; i < 4; ++i) {
        const float v = ok ? acc[i] : -3.0e38f;
        if (v > bv[i][KT - 1]) {
          float tv = v; int ti = gc;
#pragma unroll
          for (int s = 0; s < KT; ++s) {
            if (tv > bv[i][s]) {
              float ov = bv[i][s]; int oi = bi[i][s];
              bv[i][s] = tv; bi[i][s] = ti; tv = ov; ti = oi;
            }
          }
        }
      }
    }
  }

  __syncthreads();
  float* mv = (float*)smem;
  int* mi = (int*)(smem + 20480);
#pragma unroll
  for (int i = 0; i < 4; ++i) {
    const int row = wv * 16 + quad * 4 + i;
#pragma unroll
    for (int t = 0; t < KT; ++t) {
      mv[row * 80 + lrow * KT + t] = bv[i][t];
      mi[row * 80 + lrow * KT + t] = bi[i][t];
    }
  }
  __syncthreads();
  if (tid < 64) {
    const int gr = row0 + tid;
    if (gr < Bb) {
      float tv5[KT]; int ti5[KT];
#pragma unroll
      for (int t = 0; t < KT; ++t) { tv5[t] = -3.0e38f; ti5[t] = 0x7fffffff; }
      for (int m = 0; m < 80; ++m) {
        float v = mv[tid * 80 + m]; int id = mi[tid * 80 + m];
        if (v > tv5[KT - 1] || (v == tv5[KT - 1] && id < ti5[KT - 1])) {
#pragma unroll
          for (int s = 0; s < KT; ++s) {
            if (v > tv5[s] || (v == tv5[s] && id < ti5[s])) {
              float ov = tv5[s]; int oi = ti5[s];
              tv5[s] = v; ti5[s] = id; v = ov; id = oi;
            }
          }
        }
      }
#pragma unroll
      for (int t = 0; t < KT; ++t) {
        cval[gr * (CH_N * KT) + chunk * KT + t] = tv5[t];
        cidx[gr * (CH_N * KT) + chunk * KT + t] = ti5[t];
      }
    }
  }
}

// ---------------- final ----------------
__global__ __launch_bounds__(256) void k_final(const float* __restrict__ cval,
    const int* __restrict__ cidx, const int* __restrict__ y,
    const float* __restrict__ p_lc, float* __restrict__ out_final) {
  const int b = blockIdx.x * 256 + threadIdx.x;
  if (b >= Bb) return;
  float tv5[KT]; int ti5[KT];
#pragma unroll
  for (int t = 0; t < KT; ++t) { tv5[t] = -3.0e38f; ti5[t] = 0x7fffffff; }
#pragma unroll
  for (int m = 0; m < CH_N * KT; ++m) {
    float v = cval[b * (CH_N * KT) + m]; int id = cidx[b * (CH_N * KT) + m];
    if (v > tv5[KT - 1] || (v == tv5[KT - 1] && id < ti5[KT - 1])) {
#pragma unroll
      for (int t = 0; t < KT; ++t) {
        if (v > tv5[t] || (v == tv5[t] && id < ti5[t])) {
          float ov = tv5[t]; int oi = ti5[t];
          tv5[t] = v; ti5[t] = id; v = ov; id = oi;
        }
      }
    }
  }
  float w[KT]; int cls[KT];
#pragma unroll
  for (int t = 0; t < KT; ++t) { w[t] = expf(tv5[t]); cls[t] = y[ti5[t]]; }
  float m = -3.0e38f;
  for (int c = 0; c < Cc; ++c) {
    float f = 0.f;
#pragma unroll
    for (int t = 0; t < KT; ++t) f += (cls[t] == c) ? w[t] : 0.f;
    m = fmaxf(m, f);
  }
  float s = 0.f;
  for (int c = 0; c < Cc; ++c) {
    float f = 0.f;
#pragma unroll
    for (int t = 0; t < KT; ++t) f += (cls[t] == c) ? w[t] : 0.f;
    s += expf(f - m);
  }
  const float lse = logf(s);
  for (int c = 0; c < Cc; ++c) {
    float f = 0.f;
#pragma unroll
    for (int t = 0; t < KT; ++t) f += (cls[t] == c) ? w[t] : 0.f;
    out_final[b * Cc + c] = 0.5f * p_lc[b * Cc + c] + 0.5f * (f - m - lse);
  }
}

extern "C" void kernel_launch(void* const* d_in, const int* in_sizes, int n_in,
                              void* d_out, int out_size, void* d_ws, size_t ws_size,
                              hipStream_t stream) {
  const float* x  = (const float*)d_in[0];
  const int* erow = (const int*)d_in[1];
  const int* ecol = erow + En;
  const float* ew = (const float*)d_in[2];
  const int* y    = (const int*)d_in[3];
  const float* W1 = (const float*)d_in[5];
  const float* b1 = (const float*)d_in[6];
  const float* cw1 = (const float*)d_in[7];
  const float* cw2 = (const float*)d_in[8];
  const float* W2 = (const float*)d_in[9];
  const float* b2 = (const float*)d_in[10];
  float* out = (float*)d_out;

  float* ws = (float*)d_ws;
  size_t off = 0;
  float* plc = ws + off; off += (size_t)Bb * Cc;
  float* cval = ws + off; off += (size_t)Bb * (CH_N * KT);
  int* cidx  = (int*)(ws + off); off += (size_t)Bb * (CH_N * KT);
  int* counts = (int*)(ws + off); off += Nn;
  int* fill   = (int*)(ws + off); off += Nn;
  int* rptr   = (int*)(ws + off); off += Nn + 4;
  int2* cpair = (int2*)(ws + off); off += (size_t)2 * En;   // even offset -> 8B aligned
  unsigned short* anb = (unsigned short*)(ws + off); off += (size_t)Bb * Hd / 2;
  unsigned short* hba = (unsigned short*)(ws + off); off += (size_t)NR * Hd / 2;
  unsigned short* hbb = (unsigned short*)(ws + off); off += (size_t)NR * Hd / 2;
  unsigned short* x0b = (unsigned short*)(ws + off); off += (size_t)NR * Hd / 2;
  unsigned short* W1p = (unsigned short*)(ws + off); off += 65536 / 2;
  unsigned short* Wcp = (unsigned short*)(ws + off); off += 294912 / 2;

  k_pack_w1<<<256, 256, 0, stream>>>(W1, W1p);
  k_pack_wc<<<1152, 256, 0, stream>>>(cw1, cw2, Wcp);
  k_in<<<NR / 64, 256, 0, stream>>>(x, W1p, b1, hba, x0b);
  hipMemsetAsync(counts, 0, (size_t)2 * Nn * sizeof(int), stream);
  k_hist<<<(En + 255) / 256, 256, 0, stream>>>(erow, counts);
  k_scan2<<<(Nn + 255) / 256, 256, 0, stream>>>(counts, rptr);
  k_scatter<<<(En + 255) / 256, 256, 0, stream>>>(erow, ecol, ew, rptr, fill, cpair);
  unsigned short* hcur = hba;
  unsigned short* hnxt = hbb;
  for (int l = 0; l < Ll; ++l) {
    const float beta = logf(1.0f / (float)(l + 1) + 1.0f);
    k_fused4<<<NR / FR, 256, 0, stream>>>(rptr, cpair, hcur, x0b,
                                          Wcp + (size_t)l * 32768, hnxt, beta);
    unsigned short* t = hcur; hcur = hnxt; hnxt = t;
  }
  k_head<<<(Bb * 64) / 256, 256, 0, stream>>>(hcur, W2, b2, anb, plc, out + (size_t)Bb * Cc);
  k_simtopk<<<((Bb + 63) / 64) * CH_N, 256, 0, stream>>>(anb, cval, cidx);
  k_final<<<(Bb + 255) / 256, 256, 0, stream>>>(cval, cidx, y, plc, out);
}